// Round 1
// baseline (980.363 us; speedup 1.0000x reference)
//
#include <hip/hip_runtime.h>
#include <hip/hip_bf16.h>

#define N0 50000
#define N1 100000
#define N2 25000
#define E00 200000
#define E11 200000
#define E10 100000
#define E21 50000
#define HID 128
#define INC 64

// ---------------------------------------------------------------------------
// Stage 1: per node type: h = x @ W + b (bf16 out), plus per-edge-type
// attention dots a = sum_d h[n,hd,d]*att[hd,d] (fp32, computed from fp32 acc).
// Block = 128 threads (thread = output feature f). 8 nodes per iteration.
// ---------------------------------------------------------------------------
__global__ __launch_bounds__(128) void proj_kernel(
    const float* __restrict__ x, const float* __restrict__ W,
    const float* __restrict__ bias,
    __hip_bfloat16* __restrict__ hout, int N,
    const float* __restrict__ av0, float* __restrict__ ao0,
    const float* __restrict__ av1, float* __restrict__ ao1,
    const float* __restrict__ av2, float* __restrict__ ao2,
    const float* __restrict__ av3, float* __restrict__ ao3)
{
    __shared__ float Wl[INC * HID];   // 32 KB
    __shared__ float xl[8 * INC];     // 2 KB
    const int tid = threadIdx.x;

    for (int i = tid; i < INC * HID; i += 128) Wl[i] = W[i];
    const float bf  = bias[tid];
    const float at0 = av0 ? av0[tid] : 0.f;
    const float at1 = av1 ? av1[tid] : 0.f;
    const float at2 = av2 ? av2[tid] : 0.f;
    const float at3 = av3 ? av3[tid] : 0.f;
    const int head = tid >> 4;

    for (int base = blockIdx.x * 8; base < N; base += gridDim.x * 8) {
        __syncthreads();  // protect xl (and first-iter Wl) before overwrite
        for (int i = tid; i < 8 * INC; i += 128) {
            int j = i >> 6, g = i & 63;
            int n = base + j;
            xl[i] = (n < N) ? x[(size_t)n * INC + g] : 0.f;
        }
        __syncthreads();

        float acc[8];
#pragma unroll
        for (int j = 0; j < 8; ++j) acc[j] = bf;
        for (int g = 0; g < INC; ++g) {
            float w = Wl[g * HID + tid];
#pragma unroll
            for (int j = 0; j < 8; ++j) acc[j] += xl[j * INC + g] * w;
        }

        int nrem = N - base; if (nrem > 8) nrem = 8;
        for (int j = 0; j < nrem; ++j)
            hout[(size_t)(base + j) * HID + tid] = __float2bfloat16(acc[j]);

        // attention dots: reduce over the 16 d-lanes of each head
#pragma unroll
        for (int p = 0; p < 4; ++p) {
            const float* av = (p == 0) ? av0 : (p == 1) ? av1 : (p == 2) ? av2 : av3;
            float*       ao = (p == 0) ? ao0 : (p == 1) ? ao1 : (p == 2) ? ao2 : ao3;
            float        at = (p == 0) ? at0 : (p == 1) ? at1 : (p == 2) ? at2 : at3;
            if (!av) continue;
            for (int j = 0; j < nrem; ++j) {
                float pr = acc[j] * at;
                pr += __shfl_xor(pr, 1);
                pr += __shfl_xor(pr, 2);
                pr += __shfl_xor(pr, 4);
                pr += __shfl_xor(pr, 8);
                if ((tid & 15) == 0) ao[(size_t)(base + j) * 8 + head] = pr;
            }
        }
    }
}

// ---------------------------------------------------------------------------
// Stage 2: softmax denominators. No max-subtraction (logits are O(1)).
// ---------------------------------------------------------------------------
__global__ __launch_bounds__(256) void denom_kernel(
    const int* __restrict__ ei, int E,
    const float* __restrict__ as_, const float* __restrict__ ad_,
    float* __restrict__ den)
{
    int gid = blockIdx.x * 256 + threadIdx.x;
    if (gid >= E * 8) return;
    int e = gid >> 3, h = gid & 7;
    int s = ei[e], d = ei[E + e];
    float v = as_[s * 8 + h] + ad_[d * 8 + h];
    v = v > 0.f ? v : 0.2f * v;
    atomicAdd(&den[d * 8 + h], expf(v));
}

// ---------------------------------------------------------------------------
// Stage 3: message scatter: agg[dst][f] += h_src[f] * alpha(e,h)
// One thread per (edge, feature).
// ---------------------------------------------------------------------------
__global__ __launch_bounds__(256) void scatter_kernel(
    const int* __restrict__ ei, int E,
    const float* __restrict__ as_, const float* __restrict__ ad_,
    const float* __restrict__ den, const __hip_bfloat16* __restrict__ hs,
    float* __restrict__ agg)
{
    long gid = (long)blockIdx.x * 256 + threadIdx.x;
    if (gid >= (long)E * 128) return;
    int e = (int)(gid >> 7), f = (int)(gid & 127), h = f >> 4;
    int s = ei[e], d = ei[E + e];
    float v = as_[s * 8 + h] + ad_[d * 8 + h];
    v = v > 0.f ? v : 0.2f * v;
    float coef = expf(v) / (den[d * 8 + h] + 1e-16f);
    float m = __bfloat162float(hs[(size_t)s * 128 + f]) * coef;
    atomicAdd(&agg[(size_t)d * 128 + f], m);
}

// ---------------------------------------------------------------------------
// Stage 4: semantic attention inputs per metapath:
//   colsum[f] += sum_n relu(agg[n][f])
//   score     += sum_n sum_f q[f]*tanh( relu(agg[n]) @ k_w[:,f] + k_b[f] )
// Block = 128 threads (thread = column f). k_w in LDS as bf16.
// 16 nodes per iteration, v transposed in LDS for float4 broadcast reads.
// ---------------------------------------------------------------------------
__global__ __launch_bounds__(128) void semantic_kernel(
    const float* __restrict__ agg, int N,
    const float* __restrict__ kw, const float* __restrict__ kb,
    const float* __restrict__ q,
    float* __restrict__ colsum, float* __restrict__ score)
{
    __shared__ __hip_bfloat16 kwl[HID * HID];  // 32 KB
    __shared__ float vT[HID * 20];             // 10 KB (stride 20 => 16B-aligned rows)
    __shared__ float red[2];
    const int tid = threadIdx.x;

    for (int i4 = tid; i4 < HID * HID / 4; i4 += 128) {
        float4 w4 = ((const float4*)kw)[i4];
        kwl[i4 * 4 + 0] = __float2bfloat16(w4.x);
        kwl[i4 * 4 + 1] = __float2bfloat16(w4.y);
        kwl[i4 * 4 + 2] = __float2bfloat16(w4.z);
        kwl[i4 * 4 + 3] = __float2bfloat16(w4.w);
    }
    const float kbf = kb[tid], qf = q[tid];
    float cs = 0.f, sc = 0.f;

    for (int base = blockIdx.x * 16; base < N; base += gridDim.x * 16) {
        __syncthreads();
#pragma unroll
        for (int j = 0; j < 16; ++j) {
            float val = agg[(size_t)(base + j) * HID + tid];
            val = val > 0.f ? val : 0.f;
            cs += val;
            vT[tid * 20 + j] = val;   // vT[g][j], g = tid
        }
        __syncthreads();

        float y[16];
#pragma unroll
        for (int j = 0; j < 16; ++j) y[j] = kbf;
        for (int g = 0; g < HID; ++g) {
            float w = __bfloat162float(kwl[g * HID + tid]);
            const float4* vp = (const float4*)&vT[g * 20];
            float4 a = vp[0], b = vp[1], c = vp[2], d = vp[3];
            y[0]  += a.x * w; y[1]  += a.y * w; y[2]  += a.z * w; y[3]  += a.w * w;
            y[4]  += b.x * w; y[5]  += b.y * w; y[6]  += b.z * w; y[7]  += b.w * w;
            y[8]  += c.x * w; y[9]  += c.y * w; y[10] += c.z * w; y[11] += c.w * w;
            y[12] += d.x * w; y[13] += d.y * w; y[14] += d.z * w; y[15] += d.w * w;
        }
#pragma unroll
        for (int j = 0; j < 16; ++j) sc += qf * tanhf(y[j]);
    }

    atomicAdd(&colsum[tid], cs);
#pragma unroll
    for (int off = 32; off; off >>= 1) sc += __shfl_down(sc, off);
    if ((tid & 63) == 0) red[tid >> 6] = sc;
    __syncthreads();
    if (tid == 0) atomicAdd(score, red[0] + red[1]);
}

// ---------------------------------------------------------------------------
// Stage 5: semantic softmax + pooled @ lin_w + sigmoid. One block.
// ---------------------------------------------------------------------------
__global__ __launch_bounds__(128) void final_kernel(
    const float* __restrict__ colsum, const float* __restrict__ score,
    const float* __restrict__ lw, const float* __restrict__ lb,
    float* __restrict__ out)
{
    __shared__ float red[4];
    const int tid = threadIdx.x;
    float s0 = score[0] / (float)N0;  // u00 -> cell0
    float s1 = score[1] / (float)N0;  // b10 -> cell0
    float s2 = score[2] / (float)N1;  // u11 -> cell1
    float s3 = score[3] / (float)N1;  // b21 -> cell1
    float m0 = fmaxf(s0, s1);
    float e0 = expf(s0 - m0), e1 = expf(s1 - m0);
    float a0 = e0 / (e0 + e1), a1 = e1 / (e0 + e1);
    float m1 = fmaxf(s2, s3);
    float e2 = expf(s2 - m1), e3 = expf(s3 - m1);
    float a2 = e2 / (e2 + e3), a3 = e3 / (e2 + e3);
    float p = a0 * colsum[0 * HID + tid] + a1 * colsum[1 * HID + tid]
            + a2 * colsum[2 * HID + tid] + a3 * colsum[3 * HID + tid];
    float o0 = p * lw[tid * 2 + 0];
    float o1 = p * lw[tid * 2 + 1];
#pragma unroll
    for (int off = 32; off; off >>= 1) {
        o0 += __shfl_down(o0, off);
        o1 += __shfl_down(o1, off);
    }
    if ((tid & 63) == 0) { red[(tid >> 6) * 2] = o0; red[(tid >> 6) * 2 + 1] = o1; }
    __syncthreads();
    if (tid == 0) {
        float z0 = red[0] + red[2] + lb[0];
        float z1 = red[1] + red[3] + lb[1];
        out[0] = 1.f / (1.f + expf(-z0));
        out[1] = 1.f / (1.f + expf(-z1));
    }
}

extern "C" void kernel_launch(void* const* d_in, const int* in_sizes, int n_in,
                              void* d_out, int out_size, void* d_ws, size_t ws_size,
                              hipStream_t stream)
{
    const float* x0  = (const float*)d_in[0];
    const float* x1  = (const float*)d_in[1];
    const float* x2  = (const float*)d_in[2];
    const int* ei00  = (const int*)d_in[3];
    const int* ei11  = (const int*)d_in[4];
    const int* ei10  = (const int*)d_in[5];
    const int* ei21  = (const int*)d_in[6];
    const float* W0  = (const float*)d_in[7];  const float* b0 = (const float*)d_in[8];
    const float* W1  = (const float*)d_in[9];  const float* b1 = (const float*)d_in[10];
    const float* W2  = (const float*)d_in[11]; const float* b2 = (const float*)d_in[12];
    const float* as00 = (const float*)d_in[13]; const float* ad00 = (const float*)d_in[14];
    const float* as11 = (const float*)d_in[15]; const float* ad11 = (const float*)d_in[16];
    const float* as10 = (const float*)d_in[17]; const float* ad10 = (const float*)d_in[18];
    const float* as21 = (const float*)d_in[19]; const float* ad21 = (const float*)d_in[20];
    const float* kw  = (const float*)d_in[21]; const float* kb  = (const float*)d_in[22];
    const float* q   = (const float*)d_in[23];
    const float* lw  = (const float*)d_in[24]; const float* lb  = (const float*)d_in[25];
    float* out = (float*)d_out;

    // ---- workspace layout (bump allocator, 256B aligned) ----
    char* p = (char*)d_ws;
    auto alloc = [&](size_t bytes) {
        char* r = p;
        p += (bytes + 255) & ~(size_t)255;
        return r;
    };
    __hip_bfloat16* h0 = (__hip_bfloat16*)alloc((size_t)N0 * HID * 2);
    __hip_bfloat16* h1 = (__hip_bfloat16*)alloc((size_t)N1 * HID * 2);
    __hip_bfloat16* h2 = (__hip_bfloat16*)alloc((size_t)N2 * HID * 2);
    float* o_as00 = (float*)alloc((size_t)N0 * 8 * 4);
    float* o_ad00 = (float*)alloc((size_t)N0 * 8 * 4);
    float* o_as11 = (float*)alloc((size_t)N1 * 8 * 4);
    float* o_ad11 = (float*)alloc((size_t)N1 * 8 * 4);
    float* o_as10 = (float*)alloc((size_t)N1 * 8 * 4);  // src of b10 = cell1
    float* o_ad10 = (float*)alloc((size_t)N0 * 8 * 4);  // dst of b10 = cell0
    float* o_as21 = (float*)alloc((size_t)N2 * 8 * 4);  // src of b21 = cell2
    float* o_ad21 = (float*)alloc((size_t)N1 * 8 * 4);  // dst of b21 = cell1
    // ---- zero region start ----
    char* zstart = p;
    float* den00 = (float*)alloc((size_t)N0 * 8 * 4);
    float* den11 = (float*)alloc((size_t)N1 * 8 * 4);
    float* den10 = (float*)alloc((size_t)N0 * 8 * 4);
    float* den21 = (float*)alloc((size_t)N1 * 8 * 4);
    float* agg0 = (float*)alloc((size_t)N0 * HID * 4);  // u00 -> cell0
    float* agg1 = (float*)alloc((size_t)N0 * HID * 4);  // b10 -> cell0
    float* agg2 = (float*)alloc((size_t)N1 * HID * 4);  // u11 -> cell1
    float* agg3 = (float*)alloc((size_t)N1 * HID * 4);  // b21 -> cell1
    float* colsum = (float*)alloc(4 * HID * 4);
    float* score  = (float*)alloc(4 * 4);
    size_t zbytes = (size_t)(p - zstart);

    hipMemsetAsync(zstart, 0, zbytes, stream);

    // projections + attention dots
    proj_kernel<<<1024, 128, 0, stream>>>(x0, W0, b0, h0, N0,
        as00, o_as00, ad00, o_ad00, ad10, o_ad10, nullptr, nullptr);
    proj_kernel<<<1024, 128, 0, stream>>>(x1, W1, b1, h1, N1,
        as11, o_as11, ad11, o_ad11, as10, o_as10, ad21, o_ad21);
    proj_kernel<<<1024, 128, 0, stream>>>(x2, W2, b2, h2, N2,
        as21, o_as21, nullptr, nullptr, nullptr, nullptr, nullptr, nullptr);

    // softmax denominators
    denom_kernel<<<(E00 * 8 + 255) / 256, 256, 0, stream>>>(ei00, E00, o_as00, o_ad00, den00);
    denom_kernel<<<(E11 * 8 + 255) / 256, 256, 0, stream>>>(ei11, E11, o_as11, o_ad11, den11);
    denom_kernel<<<(E10 * 8 + 255) / 256, 256, 0, stream>>>(ei10, E10, o_as10, o_ad10, den10);
    denom_kernel<<<(E21 * 8 + 255) / 256, 256, 0, stream>>>(ei21, E21, o_as21, o_ad21, den21);

    // message scatter
    scatter_kernel<<<(int)(((long)E00 * 128 + 255) / 256), 256, 0, stream>>>(
        ei00, E00, o_as00, o_ad00, den00, h0, agg0);
    scatter_kernel<<<(int)(((long)E10 * 128 + 255) / 256), 256, 0, stream>>>(
        ei10, E10, o_as10, o_ad10, den10, h1, agg1);
    scatter_kernel<<<(int)(((long)E11 * 128 + 255) / 256), 256, 0, stream>>>(
        ei11, E11, o_as11, o_ad11, den11, h1, agg2);
    scatter_kernel<<<(int)(((long)E21 * 128 + 255) / 256), 256, 0, stream>>>(
        ei21, E21, o_as21, o_ad21, den21, h2, agg3);

    // semantic reductions (score order: [u00, b10, u11, b21])
    semantic_kernel<<<768, 128, 0, stream>>>(agg0, N0, kw, kb, q, colsum + 0 * HID, score + 0);
    semantic_kernel<<<768, 128, 0, stream>>>(agg1, N0, kw, kb, q, colsum + 1 * HID, score + 1);
    semantic_kernel<<<768, 128, 0, stream>>>(agg2, N1, kw, kb, q, colsum + 2 * HID, score + 2);
    semantic_kernel<<<768, 128, 0, stream>>>(agg3, N1, kw, kb, q, colsum + 3 * HID, score + 3);

    final_kernel<<<1, 128, 0, stream>>>(colsum, score, lw, lb, out);
}

// Round 3
// 504.332 us; speedup vs baseline: 1.9439x; 1.9439x over previous
//
#include <hip/hip_runtime.h>
#include <hip/hip_fp16.h>

#define N0 50000
#define N1 100000
#define N2 25000
#define E00 200000
#define E11 200000
#define E10 100000
#define E21 50000
#define HID 128
#define INC 64

typedef _Float16 half8 __attribute__((ext_vector_type(8)));
typedef float float4v __attribute__((ext_vector_type(4)));

__device__ __forceinline__ float lane_bcast(float v, int g) {
    return __int_as_float(__builtin_amdgcn_readlane(__float_as_int(v), g));
}

// ---------------------------------------------------------------------------
// Stage 1: h = x @ W + b  (f16 half2 out, layout [N][64] half2 = feature pairs
// (2l,2l+1) in element l), plus per-edge-type attention dots (fp32).
// Wave processes 8 nodes: lane l holds x[n][l]; broadcast via v_readlane;
// W read as ds_read_b64 (features 2l, 2l+1).
// ---------------------------------------------------------------------------
__global__ __launch_bounds__(256) void proj_kernel(
    const float* __restrict__ x, const float* __restrict__ W,
    const float* __restrict__ bias, __half2* __restrict__ hout, int N,
    const float* __restrict__ av0, float* __restrict__ ao0,
    const float* __restrict__ av1, float* __restrict__ ao1,
    const float* __restrict__ av2, float* __restrict__ ao2,
    const float* __restrict__ av3, float* __restrict__ ao3)
{
    __shared__ float Wl[INC * HID];   // 32 KB
    const int tid = threadIdx.x;
    const int lane = tid & 63, wv = tid >> 6;

    for (int i = tid; i < INC * HID; i += 256) Wl[i] = W[i];
    __syncthreads();

    const float2 bv = *(const float2*)&bias[2 * lane];
    const float* avs[4] = {av0, av1, av2, av3};
    float* aos[4] = {ao0, ao1, ao2, ao3};
    float2 ats[4];
#pragma unroll
    for (int p = 0; p < 4; ++p)
        ats[p] = avs[p] ? *(const float2*)&avs[p][2 * lane] : make_float2(0.f, 0.f);

    const int wid = blockIdx.x * 4 + wv;
    const int nwaves = gridDim.x * 4;
    for (int base = wid * 8; base < N; base += nwaves * 8) {
        float xv[8];
#pragma unroll
        for (int j = 0; j < 8; ++j) xv[j] = x[(size_t)(base + j) * INC + lane];

        float2 acc[8];
#pragma unroll
        for (int j = 0; j < 8; ++j) acc[j] = bv;

#pragma unroll
        for (int g = 0; g < INC; ++g) {
            float2 w = *(const float2*)&Wl[g * HID + 2 * lane];
#pragma unroll
            for (int j = 0; j < 8; ++j) {
                float xg = lane_bcast(xv[j], g);
                acc[j].x += xg * w.x;
                acc[j].y += xg * w.y;
            }
        }

#pragma unroll
        for (int j = 0; j < 8; ++j)
            hout[(size_t)(base + j) * 64 + lane] = __floats2half2_rn(acc[j].x, acc[j].y);

        // attention dots: features 2l,2l+1 belong to head l>>3; reduce 8 lanes
#pragma unroll
        for (int p = 0; p < 4; ++p) {
            if (!avs[p]) continue;
#pragma unroll
            for (int j = 0; j < 8; ++j) {
                float pr = acc[j].x * ats[p].x + acc[j].y * ats[p].y;
                pr += __shfl_xor(pr, 1);
                pr += __shfl_xor(pr, 2);
                pr += __shfl_xor(pr, 4);
                if ((lane & 7) == 0)
                    aos[p][(size_t)(base + j) * 8 + (lane >> 3)] = pr;
            }
        }
    }
}

// ---------------------------------------------------------------------------
// Stage 2: per (edge, head): w = exp(leaky_relu(a_s+a_d)); store w; den += w.
// (no max-subtraction: logits are O(1))
// ---------------------------------------------------------------------------
__global__ __launch_bounds__(256) void denom_kernel(
    const int* __restrict__ ei, int E,
    const float* __restrict__ as_, const float* __restrict__ ad_,
    float* __restrict__ warr, float* __restrict__ den)
{
    int gid = blockIdx.x * 256 + threadIdx.x;
    if (gid >= E * 8) return;
    int e = gid >> 3, h = gid & 7;
    int s = ei[e], d = ei[E + e];
    float v = as_[s * 8 + h] + ad_[d * 8 + h];
    v = v > 0.f ? v : 0.2f * v;
    float w = __expf(v);
    warr[gid] = w;
    atomicAdd(&den[d * 8 + h], w);
}

// ---------------------------------------------------------------------------
// Stage 3: wave per edge; lane l = feature pair (2l,2l+1), head l>>3.
// agg (f16) += h_src * alpha via packed f16 atomics (global_atomic_pk_add_f16).
// ---------------------------------------------------------------------------
__global__ __launch_bounds__(256) void scatter_kernel(
    const int* __restrict__ ei, int E,
    const float* __restrict__ warr, const float* __restrict__ den,
    const __half2* __restrict__ hs, __half2* __restrict__ agg)
{
    int gid = blockIdx.x * 256 + threadIdx.x;
    int e = gid >> 6, l = gid & 63;
    if (e >= E) return;
    int s = ei[e], d = ei[E + e];
    int h = l >> 3;
    float w = warr[e * 8 + h];
    float dn = den[d * 8 + h];
    float alpha = w * __builtin_amdgcn_rcpf(dn + 1e-16f);
    __half2 hv = hs[(size_t)s * 64 + l];
    __half2 m = __hmul2(hv, __float2half2_rn(alpha));
    unsafeAtomicAdd(&agg[(size_t)d * 64 + l], m);  // global_atomic_pk_add_f16
}

// ---------------------------------------------------------------------------
// Stage 4: per metapath, MFMA:  Y = relu(agg) @ [k_w | lin_w]  (f16 in, f32 out)
//   score += sum_{n,f} q_f * tanh(Y[n,f] + k_b[f])     (f-tiles 0..7)
//   cs2[c] += sum_n (relu(agg[n]) @ lin_w[:,c])        (f-tile 8, cols 0,1)
// B-frags persistent in VGPRs; A-frags direct global dwordx4 loads.
// mfma_f32_16x16x32_f16: A[m=lane&15][k=(lane>>4)*8+j]; B[k][n=lane&15];
// C: col=lane&15, row=(lane>>4)*4+reg.
// ---------------------------------------------------------------------------
#define KSTR 136
__global__ __launch_bounds__(256, 2) void semantic_kernel(
    const _Float16* __restrict__ agg, int ntiles,
    const float* __restrict__ kw, const float* __restrict__ lw,
    const float* __restrict__ kb, const float* __restrict__ q,
    float* __restrict__ cs2, float* __restrict__ score)
{
    __shared__ _Float16 kwT[144 * KSTR];   // ~38.3 KB, f-major, +8 halves pad
    __shared__ float redv[3];
    const int tid = threadIdx.x;
    const int lane = tid & 63, wv = tid >> 6;
    const int fi = lane & 15, hi = lane >> 4;

    // stage kwT[f][g] = kw[g][f] (f16); rows 128..143 = lin_w cols 0,1 + zeros
    for (int idx = tid; idx < 128 * 128; idx += 256) {
        int g = idx >> 7, f = idx & 127;
        kwT[f * KSTR + g] = (_Float16)kw[idx];
    }
    for (int idx = tid; idx < 16 * 128; idx += 256) {
        int f2 = idx >> 7, g = idx & 127;
        kwT[(128 + f2) * KSTR + g] = (_Float16)((f2 < 2) ? lw[g * 2 + f2] : 0.f);
    }
    if (tid < 3) redv[tid] = 0.f;
    __syncthreads();

    // persistent B fragments
    half8 bf[9][4];
#pragma unroll
    for (int ft = 0; ft < 9; ++ft)
#pragma unroll
        for (int kk = 0; kk < 4; ++kk)
            bf[ft][kk] = *(const half8*)&kwT[(ft * 16 + fi) * KSTR + kk * 32 + hi * 8];

    float qv[8], kbv[8];
#pragma unroll
    for (int ft = 0; ft < 8; ++ft) {
        qv[ft] = q[ft * 16 + fi];
        kbv[ft] = kb[ft * 16 + fi];
    }

    float sc = 0.f, csv = 0.f;
    const char* aggb = (const char*)agg;
    const int nw = gridDim.x * 4;
    for (int t = blockIdx.x * 4 + wv; t < ntiles; t += nw) {
        const char* rowp = aggb + ((size_t)(t * 16 + fi) * 256 + hi * 16);
        half8 af[4];
        af[0] = *(const half8*)(rowp);
        af[1] = *(const half8*)(rowp + 64);
        af[2] = *(const half8*)(rowp + 128);
        af[3] = *(const half8*)(rowp + 192);
#pragma unroll
        for (int kk = 0; kk < 4; ++kk) {
            half8 v = af[kk];
#pragma unroll
            for (int j = 0; j < 8; ++j) v[j] = (v[j] > (_Float16)0.f) ? v[j] : (_Float16)0.f;
            af[kk] = v;
        }
#pragma unroll
        for (int ft = 0; ft < 8; ++ft) {
            float4v c = {0.f, 0.f, 0.f, 0.f};
            c = __builtin_amdgcn_mfma_f32_16x16x32_f16(af[0], bf[ft][0], c, 0, 0, 0);
            c = __builtin_amdgcn_mfma_f32_16x16x32_f16(af[1], bf[ft][1], c, 0, 0, 0);
            c = __builtin_amdgcn_mfma_f32_16x16x32_f16(af[2], bf[ft][2], c, 0, 0, 0);
            c = __builtin_amdgcn_mfma_f32_16x16x32_f16(af[3], bf[ft][3], c, 0, 0, 0);
#pragma unroll
            for (int r = 0; r < 4; ++r) {
                float y = c[r] + kbv[ft];
                float e = __expf(2.f * y);
                sc += qv[ft] * (1.f - 2.f * __builtin_amdgcn_rcpf(e + 1.f));
            }
        }
        {
            float4v c = {0.f, 0.f, 0.f, 0.f};
            c = __builtin_amdgcn_mfma_f32_16x16x32_f16(af[0], bf[8][0], c, 0, 0, 0);
            c = __builtin_amdgcn_mfma_f32_16x16x32_f16(af[1], bf[8][1], c, 0, 0, 0);
            c = __builtin_amdgcn_mfma_f32_16x16x32_f16(af[2], bf[8][2], c, 0, 0, 0);
            c = __builtin_amdgcn_mfma_f32_16x16x32_f16(af[3], bf[8][3], c, 0, 0, 0);
            csv += c[0] + c[1] + c[2] + c[3];
        }
    }

    // score: reduce over all 64 lanes, then block LDS, then one global atomic
#pragma unroll
    for (int off = 1; off < 64; off <<= 1) sc += __shfl_xor(sc, off);
    // csv: lane fi holds column fi; reduce over the 4 hi-groups
    csv += __shfl_xor(csv, 16);
    csv += __shfl_xor(csv, 32);
    if (lane == 0) atomicAdd(&redv[0], sc);
    if (hi == 0 && fi < 2) atomicAdd(&redv[1 + fi], csv);
    __syncthreads();
    if (tid == 0) {
        atomicAdd(score, redv[0]);
        atomicAdd(&cs2[0], redv[1]);
        atomicAdd(&cs2[1], redv[2]);
    }
}

// ---------------------------------------------------------------------------
// Stage 5: semantic softmax + classifier + sigmoid. One thread.
// ---------------------------------------------------------------------------
__global__ void final_kernel(const float* __restrict__ cs2,
                             const float* __restrict__ score,
                             const float* __restrict__ lb,
                             float* __restrict__ out)
{
    float s0 = score[0] / (float)N0;  // u00 -> cell0
    float s1 = score[1] / (float)N0;  // b10 -> cell0
    float s2 = score[2] / (float)N1;  // u11 -> cell1
    float s3 = score[3] / (float)N1;  // b21 -> cell1
    float m0 = fmaxf(s0, s1);
    float e0 = expf(s0 - m0), e1 = expf(s1 - m0);
    float a0 = e0 / (e0 + e1), a1 = e1 / (e0 + e1);
    float m1 = fmaxf(s2, s3);
    float e2 = expf(s2 - m1), e3 = expf(s3 - m1);
    float a2 = e2 / (e2 + e3), a3 = e3 / (e2 + e3);
    float z0 = a0 * cs2[0] + a1 * cs2[2] + a2 * cs2[4] + a3 * cs2[6] + lb[0];
    float z1 = a0 * cs2[1] + a1 * cs2[3] + a2 * cs2[5] + a3 * cs2[7] + lb[1];
    out[0] = 1.f / (1.f + expf(-z0));
    out[1] = 1.f / (1.f + expf(-z1));
}

extern "C" void kernel_launch(void* const* d_in, const int* in_sizes, int n_in,
                              void* d_out, int out_size, void* d_ws, size_t ws_size,
                              hipStream_t stream)
{
    const float* x0  = (const float*)d_in[0];
    const float* x1  = (const float*)d_in[1];
    const float* x2  = (const float*)d_in[2];
    const int* ei00  = (const int*)d_in[3];
    const int* ei11  = (const int*)d_in[4];
    const int* ei10  = (const int*)d_in[5];
    const int* ei21  = (const int*)d_in[6];
    const float* W0  = (const float*)d_in[7];  const float* b0 = (const float*)d_in[8];
    const float* W1  = (const float*)d_in[9];  const float* b1 = (const float*)d_in[10];
    const float* W2  = (const float*)d_in[11]; const float* b2 = (const float*)d_in[12];
    const float* as00 = (const float*)d_in[13]; const float* ad00 = (const float*)d_in[14];
    const float* as11 = (const float*)d_in[15]; const float* ad11 = (const float*)d_in[16];
    const float* as10 = (const float*)d_in[17]; const float* ad10 = (const float*)d_in[18];
    const float* as21 = (const float*)d_in[19]; const float* ad21 = (const float*)d_in[20];
    const float* kw  = (const float*)d_in[21]; const float* kb  = (const float*)d_in[22];
    const float* q   = (const float*)d_in[23];
    const float* lw  = (const float*)d_in[24]; const float* lb  = (const float*)d_in[25];
    float* out = (float*)d_out;

    char* p = (char*)d_ws;
    auto alloc = [&](size_t bytes) {
        char* r = p;
        p += (bytes + 255) & ~(size_t)255;
        return r;
    };
    __half2* h0 = (__half2*)alloc((size_t)N0 * 256);   // [N][64] half2
    __half2* h1 = (__half2*)alloc((size_t)N1 * 256);
    __half2* h2 = (__half2*)alloc((size_t)N2 * 256);
    float* o_as00 = (float*)alloc((size_t)N0 * 32);
    float* o_ad00 = (float*)alloc((size_t)N0 * 32);
    float* o_as11 = (float*)alloc((size_t)N1 * 32);
    float* o_ad11 = (float*)alloc((size_t)N1 * 32);
    float* o_as10 = (float*)alloc((size_t)N1 * 32);   // src of b10 = cell1
    float* o_ad10 = (float*)alloc((size_t)N0 * 32);   // dst of b10 = cell0
    float* o_as21 = (float*)alloc((size_t)N2 * 32);   // src of b21 = cell2
    float* o_ad21 = (float*)alloc((size_t)N1 * 32);   // dst of b21 = cell1
    float* w00 = (float*)alloc((size_t)E00 * 32);
    float* w11 = (float*)alloc((size_t)E11 * 32);
    float* w10 = (float*)alloc((size_t)E10 * 32);
    float* w21 = (float*)alloc((size_t)E21 * 32);
    // ---- zero region ----
    char* zstart = p;
    float* den00 = (float*)alloc((size_t)N0 * 32);
    float* den11 = (float*)alloc((size_t)N1 * 32);
    float* den10 = (float*)alloc((size_t)N0 * 32);
    float* den21 = (float*)alloc((size_t)N1 * 32);
    __half2* agg0 = (__half2*)alloc((size_t)N0 * 256);  // u00 -> cell0
    __half2* agg1 = (__half2*)alloc((size_t)N0 * 256);  // b10 -> cell0
    __half2* agg2 = (__half2*)alloc((size_t)N1 * 256);  // u11 -> cell1
    __half2* agg3 = (__half2*)alloc((size_t)N1 * 256);  // b21 -> cell1
    float* colsum2 = (float*)alloc(8 * 4);              // [metapath][2]
    float* score   = (float*)alloc(4 * 4);
    size_t zbytes = (size_t)(p - zstart);

    (void)hipMemsetAsync(zstart, 0, zbytes, stream);

    proj_kernel<<<(N0 + 31) / 32, 256, 0, stream>>>(x0, W0, b0, h0, N0,
        as00, o_as00, ad00, o_ad00, ad10, o_ad10, nullptr, nullptr);
    proj_kernel<<<(N1 + 31) / 32, 256, 0, stream>>>(x1, W1, b1, h1, N1,
        as11, o_as11, ad11, o_ad11, as10, o_as10, ad21, o_ad21);
    proj_kernel<<<(N2 + 31) / 32, 256, 0, stream>>>(x2, W2, b2, h2, N2,
        as21, o_as21, nullptr, nullptr, nullptr, nullptr, nullptr, nullptr);

    denom_kernel<<<(E00 * 8 + 255) / 256, 256, 0, stream>>>(ei00, E00, o_as00, o_ad00, w00, den00);
    denom_kernel<<<(E11 * 8 + 255) / 256, 256, 0, stream>>>(ei11, E11, o_as11, o_ad11, w11, den11);
    denom_kernel<<<(E10 * 8 + 255) / 256, 256, 0, stream>>>(ei10, E10, o_as10, o_ad10, w10, den10);
    denom_kernel<<<(E21 * 8 + 255) / 256, 256, 0, stream>>>(ei21, E21, o_as21, o_ad21, w21, den21);

    scatter_kernel<<<E00 / 4, 256, 0, stream>>>(ei00, E00, w00, den00, h0, agg0);
    scatter_kernel<<<E10 / 4, 256, 0, stream>>>(ei10, E10, w10, den10, h1, agg1);
    scatter_kernel<<<E11 / 4, 256, 0, stream>>>(ei11, E11, w11, den11, h1, agg2);
    scatter_kernel<<<E21 / 4, 256, 0, stream>>>(ei21, E21, w21, den21, h2, agg3);

    semantic_kernel<<<512, 256, 0, stream>>>((const _Float16*)agg0, N0 / 16, kw, lw, kb, q, colsum2 + 0, score + 0);
    semantic_kernel<<<512, 256, 0, stream>>>((const _Float16*)agg1, N0 / 16, kw, lw, kb, q, colsum2 + 2, score + 1);
    semantic_kernel<<<512, 256, 0, stream>>>((const _Float16*)agg2, N1 / 16, kw, lw, kb, q, colsum2 + 4, score + 2);
    semantic_kernel<<<512, 256, 0, stream>>>((const _Float16*)agg3, N1 / 16, kw, lw, kb, q, colsum2 + 6, score + 3);

    final_kernel<<<1, 1, 0, stream>>>(colsum2, score, lb, out);
}

// Round 4
// 454.223 us; speedup vs baseline: 2.1583x; 1.1103x over previous
//
#include <hip/hip_runtime.h>
#include <hip/hip_fp16.h>

#define N0 50000
#define N1 100000
#define N2 25000
#define E00 200000
#define E11 200000
#define E10 100000
#define E21 50000
#define EE  550000   // E00+E10+E11+E21 (concatenated edge space)
#define ND  300000   // 50000(u00)+50000(b10)+100000(u11)+100000(b21) dst slots
#define NB  293      // ceil(ND/1024) scan blocks
#define HID 128
#define INC 64

typedef _Float16 half8 __attribute__((ext_vector_type(8)));
typedef float float4v __attribute__((ext_vector_type(4)));

__device__ __forceinline__ float lane_bcast(float v, int g) {
    return __int_as_float(__builtin_amdgcn_readlane(__float_as_int(v), g));
}

// ---------------------------------------------------------------------------
// Stage 1: h = x @ W + b  (f16 half2 out, layout [N][64] half2), plus
// per-edge-type attention dots (fp32). Persistent grid: block stages W once,
// then grid-strides over many node batches.
// ---------------------------------------------------------------------------
__global__ __launch_bounds__(256) void proj_kernel(
    const float* __restrict__ x, const float* __restrict__ W,
    const float* __restrict__ bias, __half2* __restrict__ hout, int N,
    const float* __restrict__ av0, float* __restrict__ ao0,
    const float* __restrict__ av1, float* __restrict__ ao1,
    const float* __restrict__ av2, float* __restrict__ ao2,
    const float* __restrict__ av3, float* __restrict__ ao3)
{
    __shared__ float Wl[INC * HID];   // 32 KB
    const int tid = threadIdx.x;
    const int lane = tid & 63, wv = tid >> 6;

    for (int i = tid; i < INC * HID; i += 256) Wl[i] = W[i];
    __syncthreads();

    const float2 bv = *(const float2*)&bias[2 * lane];
    const float* avs[4] = {av0, av1, av2, av3};
    float* aos[4] = {ao0, ao1, ao2, ao3};
    float2 ats[4];
#pragma unroll
    for (int p = 0; p < 4; ++p)
        ats[p] = avs[p] ? *(const float2*)&avs[p][2 * lane] : make_float2(0.f, 0.f);

    const int wid = blockIdx.x * 4 + wv;
    const int nwaves = gridDim.x * 4;
    for (int base = wid * 8; base < N; base += nwaves * 8) {
        float xv[8];
#pragma unroll
        for (int j = 0; j < 8; ++j) xv[j] = x[(size_t)(base + j) * INC + lane];

        float2 acc[8];
#pragma unroll
        for (int j = 0; j < 8; ++j) acc[j] = bv;

#pragma unroll
        for (int g = 0; g < INC; ++g) {
            float2 w = *(const float2*)&Wl[g * HID + 2 * lane];
#pragma unroll
            for (int j = 0; j < 8; ++j) {
                float xg = lane_bcast(xv[j], g);
                acc[j].x += xg * w.x;
                acc[j].y += xg * w.y;
            }
        }

#pragma unroll
        for (int j = 0; j < 8; ++j)
            hout[(size_t)(base + j) * 64 + lane] = __floats2half2_rn(acc[j].x, acc[j].y);

#pragma unroll
        for (int p = 0; p < 4; ++p) {
            if (!avs[p]) continue;
#pragma unroll
            for (int j = 0; j < 8; ++j) {
                float pr = acc[j].x * ats[p].x + acc[j].y * ats[p].y;
                pr += __shfl_xor(pr, 1);
                pr += __shfl_xor(pr, 2);
                pr += __shfl_xor(pr, 4);
                if ((lane & 7) == 0)
                    aos[p][(size_t)(base + j) * 8 + (lane >> 3)] = pr;
            }
        }
    }
}

// ---------------------------------------------------------------------------
// CSR build over the concatenated (edge-type, dst) slot space.
// slot bases: u00:0, b10:50000, u11:100000, b21:200000.
// ---------------------------------------------------------------------------
__device__ __forceinline__ void decode_edge(
    int e, const int* ei00, const int* ei10, const int* ei11, const int* ei21,
    int& src, int& slot)
{
    if (e < E00)                    { src = ei00[e];                       slot = ei00[E00 + e]; }
    else if (e < E00 + E10)         { int i = e - E00;                     src = ei10[i]; slot = 50000  + ei10[E10 + i]; }
    else if (e < E00 + E10 + E11)   { int i = e - E00 - E10;               src = ei11[i]; slot = 100000 + ei11[E11 + i]; }
    else                            { int i = e - E00 - E10 - E11;         src = ei21[i]; slot = 200000 + ei21[E21 + i]; }
}

__global__ __launch_bounds__(256) void count_kernel(
    const int* __restrict__ ei00, const int* __restrict__ ei10,
    const int* __restrict__ ei11, const int* __restrict__ ei21,
    int* __restrict__ cnt)
{
    int e = blockIdx.x * 256 + threadIdx.x;
    if (e >= EE) return;
    int src, slot;
    decode_edge(e, ei00, ei10, ei11, ei21, src, slot);
    atomicAdd(&cnt[slot], 1);
}

// scan1: per-1024-chunk totals
__global__ __launch_bounds__(256) void scan1_kernel(
    const int* __restrict__ cnt, int* __restrict__ part)
{
    const int tid = threadIdx.x, b = blockIdx.x;
    int i0 = b * 1024 + tid * 4;
    int s = 0;
#pragma unroll
    for (int k = 0; k < 4; ++k) { int i = i0 + k; s += (i < ND) ? cnt[i] : 0; }
#pragma unroll
    for (int off = 1; off < 64; off <<= 1) s += __shfl_xor(s, off);
    __shared__ int wt[4];
    if ((tid & 63) == 0) wt[tid >> 6] = s;
    __syncthreads();
    if (tid == 0) part[b] = wt[0] + wt[1] + wt[2] + wt[3];
}

// scan2: exclusive scan of NB partials (single block, NB <= 512)
__global__ __launch_bounds__(256) void scan2_kernel(int* __restrict__ part)
{
    const int t = threadIdx.x;
    int p0 = (2 * t     < NB) ? part[2 * t]     : 0;
    int p1 = (2 * t + 1 < NB) ? part[2 * t + 1] : 0;
    int ps = p0 + p1;
    __shared__ int sd[256];
    sd[t] = ps; __syncthreads();
    for (int d = 1; d < 256; d <<= 1) {
        int v = (t >= d) ? sd[t - d] : 0;
        __syncthreads();
        sd[t] += v;
        __syncthreads();
    }
    int exc = sd[t] - ps;
    if (2 * t     < NB) part[2 * t]     = exc;
    if (2 * t + 1 < NB) part[2 * t + 1] = exc + p0;
}

// scan3: final exclusive offsets; also initialize fill cursors
__global__ __launch_bounds__(256) void scan3_kernel(
    const int* __restrict__ cnt, const int* __restrict__ part,
    int* __restrict__ off, int* __restrict__ cursor)
{
    const int tid = threadIdx.x, b = blockIdx.x;
    const int lane = tid & 63, wv = tid >> 6;
    int i0 = b * 1024 + tid * 4;
    int v[4];
#pragma unroll
    for (int k = 0; k < 4; ++k) { int i = i0 + k; v[k] = (i < ND) ? cnt[i] : 0; }
    int ts = v[0] + v[1] + v[2] + v[3];
    int inc = ts;
#pragma unroll
    for (int d = 1; d < 64; d <<= 1) {
        int u = __shfl_up(inc, d);
        if (lane >= d) inc += u;
    }
    int wexc = inc - ts;
    __shared__ int wt[4];
    if (lane == 63) wt[wv] = inc;
    __syncthreads();
    int wbase = 0;
    for (int w = 0; w < wv; ++w) wbase += wt[w];
    int base = part[b] + wbase + wexc;
    int pre = 0;
#pragma unroll
    for (int k = 0; k < 4; ++k) {
        int i = i0 + k;
        if (i < ND) { off[i] = base + pre; cursor[i] = base + pre; }
        pre += v[k];
    }
}

__global__ __launch_bounds__(256) void fill_kernel(
    const int* __restrict__ ei00, const int* __restrict__ ei10,
    const int* __restrict__ ei11, const int* __restrict__ ei21,
    int* __restrict__ cursor, int* __restrict__ srcs)
{
    int e = blockIdx.x * 256 + threadIdx.x;
    if (e >= EE) return;
    int src, slot;
    decode_edge(e, ei00, ei10, ei11, ei21, src, slot);
    int pos = atomicAdd(&cursor[slot], 1);
    srcs[pos] = src;
}

// ---------------------------------------------------------------------------
// Gather: one wave per dst slot. Lane l = feature pair (2l,2l+1), head l>>3.
// Online softmax: acc = sum w*h; sumw = sum w; agg = acc * rcp(sumw+eps).
// Each agg row written exactly once -> no memset, no atomics.
// ---------------------------------------------------------------------------
__global__ __launch_bounds__(256) void gather_kernel(
    const int* __restrict__ cnt, const int* __restrict__ off,
    const int* __restrict__ srcs,
    const __half2* __restrict__ h0, const __half2* __restrict__ h1,
    const __half2* __restrict__ h2,
    const float* __restrict__ as00, const float* __restrict__ ad00,
    const float* __restrict__ as10, const float* __restrict__ ad10,
    const float* __restrict__ as11, const float* __restrict__ ad11,
    const float* __restrict__ as21, const float* __restrict__ ad21,
    __half2* __restrict__ agg)
{
    int gid = blockIdx.x * 256 + threadIdx.x;
    int slot = gid >> 6, l = gid & 63;
    if (slot >= ND) return;
    const __half2* hs; const float* asp; const float* adp; int d;
    if (slot < 50000)       { hs = h0; asp = as00; adp = ad00; d = slot; }
    else if (slot < 100000) { hs = h1; asp = as10; adp = ad10; d = slot - 50000; }
    else if (slot < 200000) { hs = h1; asp = as11; adp = ad11; d = slot - 100000; }
    else                    { hs = h2; asp = as21; adp = ad21; d = slot - 200000; }
    const int h = l >> 3;
    const float ad = adp[d * 8 + h];
    const int deg = cnt[slot], st = off[slot];

    float ax = 0.f, ay = 0.f, sw = 0.f;
    auto body = [&](int s) {
        float v = asp[s * 8 + h] + ad;
        v = v > 0.f ? v : 0.2f * v;
        float w = __expf(v);
        float2 hf = __half22float2(hs[(size_t)s * 64 + l]);
        ax += w * hf.x;
        ay += w * hf.y;
        sw += w;
    };
    int i = 0;
    for (; i + 4 <= deg; i += 4) {
        int s0 = srcs[st + i], s1 = srcs[st + i + 1];
        int s2 = srcs[st + i + 2], s3 = srcs[st + i + 3];
        body(s0); body(s1); body(s2); body(s3);
    }
    for (; i < deg; ++i) body(srcs[st + i]);

    float rr = __builtin_amdgcn_rcpf(sw + 1e-16f);
    agg[(size_t)slot * 64 + l] = __floats2half2_rn(ax * rr, ay * rr);
}

// ---------------------------------------------------------------------------
// Stage 4: per metapath, MFMA:  Y = relu(agg) @ [k_w | lin_w]  (f16 in, f32 out)
// ---------------------------------------------------------------------------
#define KSTR 136
__global__ __launch_bounds__(256, 2) void semantic_kernel(
    const _Float16* __restrict__ agg, int ntiles,
    const float* __restrict__ kw, const float* __restrict__ lw,
    const float* __restrict__ kb, const float* __restrict__ q,
    float* __restrict__ cs2, float* __restrict__ score)
{
    __shared__ _Float16 kwT[144 * KSTR];
    __shared__ float redv[3];
    const int tid = threadIdx.x;
    const int lane = tid & 63, wv = tid >> 6;
    const int fi = lane & 15, hi = lane >> 4;

    for (int idx = tid; idx < 128 * 128; idx += 256) {
        int g = idx >> 7, f = idx & 127;
        kwT[f * KSTR + g] = (_Float16)kw[idx];
    }
    for (int idx = tid; idx < 16 * 128; idx += 256) {
        int f2 = idx >> 7, g = idx & 127;
        kwT[(128 + f2) * KSTR + g] = (_Float16)((f2 < 2) ? lw[g * 2 + f2] : 0.f);
    }
    if (tid < 3) redv[tid] = 0.f;
    __syncthreads();

    half8 bf[9][4];
#pragma unroll
    for (int ft = 0; ft < 9; ++ft)
#pragma unroll
        for (int kk = 0; kk < 4; ++kk)
            bf[ft][kk] = *(const half8*)&kwT[(ft * 16 + fi) * KSTR + kk * 32 + hi * 8];

    float qv[8], kbv[8];
#pragma unroll
    for (int ft = 0; ft < 8; ++ft) {
        qv[ft] = q[ft * 16 + fi];
        kbv[ft] = kb[ft * 16 + fi];
    }

    float sc = 0.f, csv = 0.f;
    const char* aggb = (const char*)agg;
    const int nw = gridDim.x * 4;
    for (int t = blockIdx.x * 4 + wv; t < ntiles; t += nw) {
        const char* rowp = aggb + ((size_t)(t * 16 + fi) * 256 + hi * 16);
        half8 af[4];
        af[0] = *(const half8*)(rowp);
        af[1] = *(const half8*)(rowp + 64);
        af[2] = *(const half8*)(rowp + 128);
        af[3] = *(const half8*)(rowp + 192);
#pragma unroll
        for (int kk = 0; kk < 4; ++kk) {
            half8 v = af[kk];
#pragma unroll
            for (int j = 0; j < 8; ++j) v[j] = (v[j] > (_Float16)0.f) ? v[j] : (_Float16)0.f;
            af[kk] = v;
        }
#pragma unroll
        for (int ft = 0; ft < 8; ++ft) {
            float4v c = {0.f, 0.f, 0.f, 0.f};
            c = __builtin_amdgcn_mfma_f32_16x16x32_f16(af[0], bf[ft][0], c, 0, 0, 0);
            c = __builtin_amdgcn_mfma_f32_16x16x32_f16(af[1], bf[ft][1], c, 0, 0, 0);
            c = __builtin_amdgcn_mfma_f32_16x16x32_f16(af[2], bf[ft][2], c, 0, 0, 0);
            c = __builtin_amdgcn_mfma_f32_16x16x32_f16(af[3], bf[ft][3], c, 0, 0, 0);
#pragma unroll
            for (int r = 0; r < 4; ++r) {
                float y = c[r] + kbv[ft];
                float e = __expf(2.f * y);
                sc += qv[ft] * (1.f - 2.f * __builtin_amdgcn_rcpf(e + 1.f));
            }
        }
        {
            float4v c = {0.f, 0.f, 0.f, 0.f};
            c = __builtin_amdgcn_mfma_f32_16x16x32_f16(af[0], bf[8][0], c, 0, 0, 0);
            c = __builtin_amdgcn_mfma_f32_16x16x32_f16(af[1], bf[8][1], c, 0, 0, 0);
            c = __builtin_amdgcn_mfma_f32_16x16x32_f16(af[2], bf[8][2], c, 0, 0, 0);
            c = __builtin_amdgcn_mfma_f32_16x16x32_f16(af[3], bf[8][3], c, 0, 0, 0);
            csv += c[0] + c[1] + c[2] + c[3];
        }
    }

#pragma unroll
    for (int off = 1; off < 64; off <<= 1) sc += __shfl_xor(sc, off);
    csv += __shfl_xor(csv, 16);
    csv += __shfl_xor(csv, 32);
    if (lane == 0) atomicAdd(&redv[0], sc);
    if (hi == 0 && fi < 2) atomicAdd(&redv[1 + fi], csv);
    __syncthreads();
    if (tid == 0) {
        atomicAdd(score, redv[0]);
        atomicAdd(&cs2[0], redv[1]);
        atomicAdd(&cs2[1], redv[2]);
    }
}

// ---------------------------------------------------------------------------
// Stage 5: semantic softmax + classifier + sigmoid. One thread.
// ---------------------------------------------------------------------------
__global__ void final_kernel(const float* __restrict__ cs2,
                             const float* __restrict__ score,
                             const float* __restrict__ lb,
                             float* __restrict__ out)
{
    float s0 = score[0] / (float)N0;
    float s1 = score[1] / (float)N0;
    float s2 = score[2] / (float)N1;
    float s3 = score[3] / (float)N1;
    float m0 = fmaxf(s0, s1);
    float e0 = expf(s0 - m0), e1 = expf(s1 - m0);
    float a0 = e0 / (e0 + e1), a1 = e1 / (e0 + e1);
    float m1 = fmaxf(s2, s3);
    float e2 = expf(s2 - m1), e3 = expf(s3 - m1);
    float a2 = e2 / (e2 + e3), a3 = e3 / (e2 + e3);
    float z0 = a0 * cs2[0] + a1 * cs2[2] + a2 * cs2[4] + a3 * cs2[6] + lb[0];
    float z1 = a0 * cs2[1] + a1 * cs2[3] + a2 * cs2[5] + a3 * cs2[7] + lb[1];
    out[0] = 1.f / (1.f + expf(-z0));
    out[1] = 1.f / (1.f + expf(-z1));
}

extern "C" void kernel_launch(void* const* d_in, const int* in_sizes, int n_in,
                              void* d_out, int out_size, void* d_ws, size_t ws_size,
                              hipStream_t stream)
{
    const float* x0  = (const float*)d_in[0];
    const float* x1  = (const float*)d_in[1];
    const float* x2  = (const float*)d_in[2];
    const int* ei00  = (const int*)d_in[3];
    const int* ei11  = (const int*)d_in[4];
    const int* ei10  = (const int*)d_in[5];
    const int* ei21  = (const int*)d_in[6];
    const float* W0  = (const float*)d_in[7];  const float* b0 = (const float*)d_in[8];
    const float* W1  = (const float*)d_in[9];  const float* b1 = (const float*)d_in[10];
    const float* W2  = (const float*)d_in[11]; const float* b2 = (const float*)d_in[12];
    const float* as00 = (const float*)d_in[13]; const float* ad00 = (const float*)d_in[14];
    const float* as11 = (const float*)d_in[15]; const float* ad11 = (const float*)d_in[16];
    const float* as10 = (const float*)d_in[17]; const float* ad10 = (const float*)d_in[18];
    const float* as21 = (const float*)d_in[19]; const float* ad21 = (const float*)d_in[20];
    const float* kw  = (const float*)d_in[21]; const float* kb  = (const float*)d_in[22];
    const float* q   = (const float*)d_in[23];
    const float* lw  = (const float*)d_in[24]; const float* lb  = (const float*)d_in[25];
    float* out = (float*)d_out;

    char* p = (char*)d_ws;
    auto alloc = [&](size_t bytes) {
        char* r = p;
        p += (bytes + 255) & ~(size_t)255;
        return r;
    };
    __half2* h0 = (__half2*)alloc((size_t)N0 * 256);   // [N][64] half2
    __half2* h1 = (__half2*)alloc((size_t)N1 * 256);
    __half2* h2 = (__half2*)alloc((size_t)N2 * 256);
    float* o_as00 = (float*)alloc((size_t)N0 * 32);
    float* o_ad00 = (float*)alloc((size_t)N0 * 32);
    float* o_as11 = (float*)alloc((size_t)N1 * 32);
    float* o_ad11 = (float*)alloc((size_t)N1 * 32);
    float* o_as10 = (float*)alloc((size_t)N1 * 32);   // src of b10 = cell1
    float* o_ad10 = (float*)alloc((size_t)N0 * 32);   // dst of b10 = cell0
    float* o_as21 = (float*)alloc((size_t)N2 * 32);   // src of b21 = cell2
    float* o_ad21 = (float*)alloc((size_t)N1 * 32);   // dst of b21 = cell1
    int* off    = (int*)alloc((size_t)ND * 4);
    int* cursor = (int*)alloc((size_t)ND * 4);
    int* part   = (int*)alloc((size_t)512 * 4);
    int* srcs   = (int*)alloc((size_t)EE * 4);
    __half2* agg = (__half2*)alloc((size_t)ND * 256);  // rows 0..50k u00 | 50k..100k b10 | 100k..200k u11 | 200k..300k b21
    // ---- zero region (contiguous) ----
    char* zstart = p;
    int* cnt = (int*)alloc((size_t)ND * 4);
    float* colsum2 = (float*)alloc(8 * 4);
    float* score   = (float*)alloc(4 * 4);
    size_t zbytes = (size_t)(p - zstart);

    (void)hipMemsetAsync(zstart, 0, zbytes, stream);

    // projections + attention dots (persistent grids)
    proj_kernel<<<640, 256, 0, stream>>>(x0, W0, b0, h0, N0,
        as00, o_as00, ad00, o_ad00, ad10, o_ad10, nullptr, nullptr);
    proj_kernel<<<1280, 256, 0, stream>>>(x1, W1, b1, h1, N1,
        as11, o_as11, ad11, o_ad11, as10, o_as10, ad21, o_ad21);
    proj_kernel<<<320, 256, 0, stream>>>(x2, W2, b2, h2, N2,
        as21, o_as21, nullptr, nullptr, nullptr, nullptr, nullptr, nullptr);

    // CSR build
    count_kernel<<<(EE + 255) / 256, 256, 0, stream>>>(ei00, ei10, ei11, ei21, cnt);
    scan1_kernel<<<NB, 256, 0, stream>>>(cnt, part);
    scan2_kernel<<<1, 256, 0, stream>>>(part);
    scan3_kernel<<<NB, 256, 0, stream>>>(cnt, part, off, cursor);
    fill_kernel<<<(EE + 255) / 256, 256, 0, stream>>>(ei00, ei10, ei11, ei21, cursor, srcs);

    // gather (online segment softmax + weighted sum)
    gather_kernel<<<ND / 4, 256, 0, stream>>>(cnt, off, srcs, h0, h1, h2,
        o_as00, o_ad00, o_as10, o_ad10, o_as11, o_ad11, o_as21, o_ad21, agg);

    // semantic reductions (score order: [u00, b10, u11, b21])
    const _Float16* aggf = (const _Float16*)agg;
    semantic_kernel<<<512, 256, 0, stream>>>(aggf + (size_t)0 * 128,      N0 / 16, kw, lw, kb, q, colsum2 + 0, score + 0);
    semantic_kernel<<<512, 256, 0, stream>>>(aggf + (size_t)50000 * 128,  N0 / 16, kw, lw, kb, q, colsum2 + 2, score + 1);
    semantic_kernel<<<512, 256, 0, stream>>>(aggf + (size_t)100000 * 128, N1 / 16, kw, lw, kb, q, colsum2 + 4, score + 2);
    semantic_kernel<<<512, 256, 0, stream>>>(aggf + (size_t)200000 * 128, N1 / 16, kw, lw, kb, q, colsum2 + 6, score + 3);

    final_kernel<<<1, 1, 0, stream>>>(colsum2, score, lb, out);
}

// Round 5
// 331.896 us; speedup vs baseline: 2.9538x; 1.3686x over previous
//
#include <hip/hip_runtime.h>
#include <hip/hip_fp16.h>

#define N0 50000
#define N1 100000
#define N2 25000
#define E00 200000
#define E11 200000
#define E10 100000
#define E21 50000
#define EE  550000   // E00+E10+E11+E21 (concatenated edge space)
#define ND  300000   // 50000(u00)+50000(b10)+100000(u11)+100000(b21) dst slots
#define NB  293      // ceil(ND/1024) scan blocks
#define NT_ALL 18750 // ND/16 semantic tiles
#define HID 128
#define INC 64

typedef _Float16 half8 __attribute__((ext_vector_type(8)));
typedef float float4v __attribute__((ext_vector_type(4)));

// ---------------------------------------------------------------------------
// Stage 1 (fused, MFMA): per node type, h = x @ W + b (f16 [N][128]) and
// attention dots a_p = x @ (W·A_p) + b·A_p (fp32 [N][8]), where A_p is the
// 128x8 block-diagonal matrix built from att_p — so dots are 2 extra MFMA
// n-tiles instead of per-element shuffles.
// mfma_f32_16x16x32_f16: A[m=lane&15][k=(lane>>4)*8+j]; B[k][n=lane&15];
// C: col=lane&15, row=(lane>>4)*4+reg.
// ---------------------------------------------------------------------------
struct PT {
    const float* x; const float* W; const float* bias; _Float16* h;
    const float* av0; const float* av1; const float* av2; const float* av3;
    float* ao0; float* ao1; float* ao2; float* ao3;
    int N; int ntiles; int bstart; int nblocks;
};

#define WPAD 72   // halves; row stride 144 B (16B-aligned b128 frags)
#define HPAD 136  // halves; row stride 272 B (16B-aligned b128 reads)

__global__ __launch_bounds__(256) void proj_mfma(PT t0, PT t1, PT t2)
{
    __shared__ _Float16 WT[128 * WPAD];    // 18.4 KB: WT[f][g] = W[g][f]
    __shared__ _Float16 AdT[32 * WPAD];    // 4.6 KB: (W·A)^T [c][g]
    __shared__ _Float16 ht[4][16][HPAD];   // 17.4 KB: per-wave h tile
    const int tid = threadIdx.x;
    const int lane = tid & 63, wv = tid >> 6;
    const int fi = lane & 15, hi = lane >> 4;

    PT A = (blockIdx.x >= t2.bstart) ? t2 : (blockIdx.x >= t1.bstart) ? t1 : t0;

    for (int idx = tid; idx < 64 * 128; idx += 256) {
        int g = idx >> 7, f = idx & 127;
        WT[f * WPAD + g] = (_Float16)A.W[idx];
    }
    const float* avs[4] = {A.av0, A.av1, A.av2, A.av3};
    for (int idx = tid; idx < 32 * 64; idx += 256) {
        int c = idx & 31, g = idx >> 5;
        const float* av = avs[c >> 3];
        float v = 0.f;
        if (av) {
            int hh = c & 7;
#pragma unroll
            for (int d = 0; d < 16; ++d)
                v += A.W[g * 128 + hh * 16 + d] * av[hh * 16 + d];
        }
        AdT[c * WPAD + g] = (_Float16)v;
    }
    __syncthreads();

    // persistent B fragments (K=64 -> 2 k-blocks)
    half8 bfr[8][2], bd[2][2];
#pragma unroll
    for (int nt = 0; nt < 8; ++nt)
#pragma unroll
        for (int kb = 0; kb < 2; ++kb)
            bfr[nt][kb] = *(const half8*)&WT[(nt * 16 + fi) * WPAD + kb * 32 + hi * 8];
#pragma unroll
    for (int t = 0; t < 2; ++t)
#pragma unroll
        for (int kb = 0; kb < 2; ++kb)
            bd[t][kb] = *(const half8*)&AdT[(t * 16 + fi) * WPAD + kb * 32 + hi * 8];

    float bvv[8];
#pragma unroll
    for (int nt = 0; nt < 8; ++nt) bvv[nt] = A.bias[nt * 16 + fi];
    float bdc[2] = {0.f, 0.f};
    {
        int hh = fi & 7;
        const float* alo = (fi >= 8) ? A.av1 : A.av0;
        const float* ahi = (fi >= 8) ? A.av3 : A.av2;
#pragma unroll
        for (int d = 0; d < 16; ++d) {
            float bb = A.bias[hh * 16 + d];
            if (alo) bdc[0] += bb * alo[hh * 16 + d];
            if (ahi) bdc[1] += bb * ahi[hh * 16 + d];
        }
    }
    float* aolo = (fi >= 8) ? A.ao1 : A.ao0;
    float* aohi = (fi >= 8) ? A.ao3 : A.ao2;
    const bool has_hi = (A.av2 != nullptr) || (A.av3 != nullptr);

    const int stride = A.nblocks * 4;
    for (int t = (blockIdx.x - A.bstart) * 4 + wv; t < A.ntiles; t += stride) {
        const int base = t * 16;
        int rsrc = base + fi; if (rsrc >= A.N) rsrc = A.N - 1;
        const float* xp = A.x + (size_t)rsrc * 64 + hi * 8;
        float4 u0 = *(const float4*)(xp);
        float4 u1 = *(const float4*)(xp + 4);
        float4 u2 = *(const float4*)(xp + 32);
        float4 u3 = *(const float4*)(xp + 36);
        half8 a0, a1;
        a0[0] = (_Float16)u0.x; a0[1] = (_Float16)u0.y; a0[2] = (_Float16)u0.z; a0[3] = (_Float16)u0.w;
        a0[4] = (_Float16)u1.x; a0[5] = (_Float16)u1.y; a0[6] = (_Float16)u1.z; a0[7] = (_Float16)u1.w;
        a1[0] = (_Float16)u2.x; a1[1] = (_Float16)u2.y; a1[2] = (_Float16)u2.z; a1[3] = (_Float16)u2.w;
        a1[4] = (_Float16)u3.x; a1[5] = (_Float16)u3.y; a1[6] = (_Float16)u3.z; a1[7] = (_Float16)u3.w;

        float4v c[8];
#pragma unroll
        for (int nt = 0; nt < 8; ++nt) {
            float4v z = {0.f, 0.f, 0.f, 0.f};
            z = __builtin_amdgcn_mfma_f32_16x16x32_f16(a0, bfr[nt][0], z, 0, 0, 0);
            z = __builtin_amdgcn_mfma_f32_16x16x32_f16(a1, bfr[nt][1], z, 0, 0, 0);
            c[nt] = z;
        }
        float4v d0 = {0.f, 0.f, 0.f, 0.f};
        d0 = __builtin_amdgcn_mfma_f32_16x16x32_f16(a0, bd[0][0], d0, 0, 0, 0);
        d0 = __builtin_amdgcn_mfma_f32_16x16x32_f16(a1, bd[0][1], d0, 0, 0, 0);
        float4v d1 = {0.f, 0.f, 0.f, 0.f};
        if (has_hi) {
            d1 = __builtin_amdgcn_mfma_f32_16x16x32_f16(a0, bd[1][0], d1, 0, 0, 0);
            d1 = __builtin_amdgcn_mfma_f32_16x16x32_f16(a1, bd[1][1], d1, 0, 0, 0);
        }

        // h epilogue: C frags -> per-wave LDS tile -> coalesced global stores
#pragma unroll
        for (int nt = 0; nt < 8; ++nt)
#pragma unroll
            for (int r = 0; r < 4; ++r)
                ht[wv][hi * 4 + r][nt * 16 + fi] = (_Float16)(c[nt][r] + bvv[nt]);
#pragma unroll
        for (int i = 0; i < 4; ++i) {
            int row = i * 4 + hi;
            int node = base + row;
            if (node < A.N) {
                half8 v = *(const half8*)&ht[wv][row][fi * 8];
                *(half8*)(A.h + (size_t)node * 128 + fi * 8) = v;
            }
        }
        // dots: dot-tile 0 -> p0/p1, dot-tile 1 -> p2/p3; head = fi&7
        if (aolo) {
#pragma unroll
            for (int r = 0; r < 4; ++r) {
                int node = base + hi * 4 + r;
                if (node < A.N) aolo[(size_t)node * 8 + (fi & 7)] = d0[r] + bdc[0];
            }
        }
        if (aohi) {
#pragma unroll
            for (int r = 0; r < 4; ++r) {
                int node = base + hi * 4 + r;
                if (node < A.N) aohi[(size_t)node * 8 + (fi & 7)] = d1[r] + bdc[1];
            }
        }
    }
}

// ---------------------------------------------------------------------------
// CSR build over the concatenated (edge-type, dst) slot space.
// slot bases: u00:0, b10:50000, u11:100000, b21:200000.
// ---------------------------------------------------------------------------
__device__ __forceinline__ void decode_edge(
    int e, const int* ei00, const int* ei10, const int* ei11, const int* ei21,
    int& src, int& slot)
{
    if (e < E00)                    { src = ei00[e];               slot = ei00[E00 + e]; }
    else if (e < E00 + E10)         { int i = e - E00;             src = ei10[i]; slot = 50000  + ei10[E10 + i]; }
    else if (e < E00 + E10 + E11)   { int i = e - E00 - E10;       src = ei11[i]; slot = 100000 + ei11[E11 + i]; }
    else                            { int i = e - E00 - E10 - E11; src = ei21[i]; slot = 200000 + ei21[E21 + i]; }
}

__global__ __launch_bounds__(256) void count_kernel(
    const int* __restrict__ ei00, const int* __restrict__ ei10,
    const int* __restrict__ ei11, const int* __restrict__ ei21,
    int* __restrict__ cnt)
{
    int e = blockIdx.x * 256 + threadIdx.x;
    if (e >= EE) return;
    int src, slot;
    decode_edge(e, ei00, ei10, ei11, ei21, src, slot);
    atomicAdd(&cnt[slot], 1);
}

__global__ __launch_bounds__(256) void scan1_kernel(
    const int* __restrict__ cnt, int* __restrict__ part)
{
    const int tid = threadIdx.x, b = blockIdx.x;
    int i0 = b * 1024 + tid * 4;
    int s = 0;
#pragma unroll
    for (int k = 0; k < 4; ++k) { int i = i0 + k; s += (i < ND) ? cnt[i] : 0; }
#pragma unroll
    for (int off = 1; off < 64; off <<= 1) s += __shfl_xor(s, off);
    __shared__ int wt[4];
    if ((tid & 63) == 0) wt[tid >> 6] = s;
    __syncthreads();
    if (tid == 0) part[b] = wt[0] + wt[1] + wt[2] + wt[3];
}

__global__ __launch_bounds__(256) void scan2_kernel(int* __restrict__ part)
{
    const int t = threadIdx.x;
    int p0 = (2 * t     < NB) ? part[2 * t]     : 0;
    int p1 = (2 * t + 1 < NB) ? part[2 * t + 1] : 0;
    int ps = p0 + p1;
    __shared__ int sd[256];
    sd[t] = ps; __syncthreads();
    for (int d = 1; d < 256; d <<= 1) {
        int v = (t >= d) ? sd[t - d] : 0;
        __syncthreads();
        sd[t] += v;
        __syncthreads();
    }
    int exc = sd[t] - ps;
    if (2 * t     < NB) part[2 * t]     = exc;
    if (2 * t + 1 < NB) part[2 * t + 1] = exc + p0;
}

__global__ __launch_bounds__(256) void scan3_kernel(
    const int* __restrict__ cnt, const int* __restrict__ part,
    int* __restrict__ off, int* __restrict__ cursor)
{
    const int tid = threadIdx.x, b = blockIdx.x;
    const int lane = tid & 63, wv = tid >> 6;
    int i0 = b * 1024 + tid * 4;
    int v[4];
#pragma unroll
    for (int k = 0; k < 4; ++k) { int i = i0 + k; v[k] = (i < ND) ? cnt[i] : 0; }
    int ts = v[0] + v[1] + v[2] + v[3];
    int inc = ts;
#pragma unroll
    for (int d = 1; d < 64; d <<= 1) {
        int u = __shfl_up(inc, d);
        if (lane >= d) inc += u;
    }
    int wexc = inc - ts;
    __shared__ int wt[4];
    if (lane == 63) wt[wv] = inc;
    __syncthreads();
    int wbase = 0;
    for (int w = 0; w < wv; ++w) wbase += wt[w];
    int base = part[b] + wbase + wexc;
    int pre = 0;
#pragma unroll
    for (int k = 0; k < 4; ++k) {
        int i = i0 + k;
        if (i < ND) { off[i] = base + pre; cursor[i] = base + pre; }
        pre += v[k];
    }
}

__global__ __launch_bounds__(256) void fill_kernel(
    const int* __restrict__ ei00, const int* __restrict__ ei10,
    const int* __restrict__ ei11, const int* __restrict__ ei21,
    int* __restrict__ cursor, int* __restrict__ srcs)
{
    int e = blockIdx.x * 256 + threadIdx.x;
    if (e >= EE) return;
    int src, slot;
    decode_edge(e, ei00, ei10, ei11, ei21, src, slot);
    int pos = atomicAdd(&cursor[slot], 1);
    srcs[pos] = src;
}

// ---------------------------------------------------------------------------
// Gather: one wave per dst slot. Lane l = feature pair (2l,2l+1), head l>>3.
// ---------------------------------------------------------------------------
__global__ __launch_bounds__(256) void gather_kernel(
    const int* __restrict__ cnt, const int* __restrict__ off,
    const int* __restrict__ srcs,
    const __half2* __restrict__ h0, const __half2* __restrict__ h1,
    const __half2* __restrict__ h2,
    const float* __restrict__ as00, const float* __restrict__ ad00,
    const float* __restrict__ as10, const float* __restrict__ ad10,
    const float* __restrict__ as11, const float* __restrict__ ad11,
    const float* __restrict__ as21, const float* __restrict__ ad21,
    __half2* __restrict__ agg)
{
    int gid = blockIdx.x * 256 + threadIdx.x;
    int slot = gid >> 6, l = gid & 63;
    if (slot >= ND) return;
    const __half2* hs; const float* asp; const float* adp; int d;
    if (slot < 50000)       { hs = h0; asp = as00; adp = ad00; d = slot; }
    else if (slot < 100000) { hs = h1; asp = as10; adp = ad10; d = slot - 50000; }
    else if (slot < 200000) { hs = h1; asp = as11; adp = ad11; d = slot - 100000; }
    else                    { hs = h2; asp = as21; adp = ad21; d = slot - 200000; }
    const int h = l >> 3;
    const float ad = adp[d * 8 + h];
    const int deg = cnt[slot], st = off[slot];

    float ax = 0.f, ay = 0.f, sw = 0.f;
    auto body = [&](int s) {
        float v = asp[s * 8 + h] + ad;
        v = v > 0.f ? v : 0.2f * v;
        float w = __expf(v);
        float2 hf = __half22float2(hs[(size_t)s * 64 + l]);
        ax += w * hf.x;
        ay += w * hf.y;
        sw += w;
    };
    int i = 0;
    for (; i + 4 <= deg; i += 4) {
        int s0 = srcs[st + i], s1 = srcs[st + i + 1];
        int s2 = srcs[st + i + 2], s3 = srcs[st + i + 3];
        body(s0); body(s1); body(s2); body(s3);
    }
    for (; i < deg; ++i) body(srcs[st + i]);

    float rr = __builtin_amdgcn_rcpf(sw + 1e-16f);
    agg[(size_t)slot * 64 + l] = __floats2half2_rn(ax * rr, ay * rr);
}

// ---------------------------------------------------------------------------
// Stage 4 (fused over all 4 metapaths): Y = relu(agg) @ [k_w | lin_w].
// agg segments are contiguous and 16-row aligned -> tile t's metapath is
// m = t>=12500?3 : t>=6250?2 : t>=3125?1 : 0 (order u00,b10,u11,b21).
// ---------------------------------------------------------------------------
#define KSTR 136
__global__ __launch_bounds__(256, 2) void semantic_kernel(
    const _Float16* __restrict__ agg,
    const float* __restrict__ kw, const float* __restrict__ lw,
    const float* __restrict__ kb, const float* __restrict__ q,
    float* __restrict__ cs2, float* __restrict__ score)
{
    __shared__ _Float16 kwT[144 * KSTR];
    __shared__ float redv[12];
    const int tid = threadIdx.x;
    const int lane = tid & 63, wv = tid >> 6;
    const int fi = lane & 15, hi = lane >> 4;

    for (int idx = tid; idx < 128 * 128; idx += 256) {
        int g = idx >> 7, f = idx & 127;
        kwT[f * KSTR + g] = (_Float16)kw[idx];
    }
    for (int idx = tid; idx < 16 * 128; idx += 256) {
        int f2 = idx >> 7, g = idx & 127;
        kwT[(128 + f2) * KSTR + g] = (_Float16)((f2 < 2) ? lw[g * 2 + f2] : 0.f);
    }
    if (tid < 12) redv[tid] = 0.f;
    __syncthreads();

    half8 bf[9][4];
#pragma unroll
    for (int ft = 0; ft < 9; ++ft)
#pragma unroll
        for (int kk = 0; kk < 4; ++kk)
            bf[ft][kk] = *(const half8*)&kwT[(ft * 16 + fi) * KSTR + kk * 32 + hi * 8];

    float qv[8], kbv[8];
#pragma unroll
    for (int ft = 0; ft < 8; ++ft) {
        qv[ft] = q[ft * 16 + fi];
        kbv[ft] = kb[ft * 16 + fi];
    }

    float sc[4] = {0.f, 0.f, 0.f, 0.f};
    float cs[4] = {0.f, 0.f, 0.f, 0.f};
    const char* aggb = (const char*)agg;
    const int nw = gridDim.x * 4;
    for (int t = blockIdx.x * 4 + wv; t < NT_ALL; t += nw) {
        const int m = (t >= 12500) ? 3 : (t >= 6250) ? 2 : (t >= 3125) ? 1 : 0;
        const char* rowp = aggb + ((size_t)(t * 16 + fi) * 256 + hi * 16);
        half8 af[4];
        af[0] = *(const half8*)(rowp);
        af[1] = *(const half8*)(rowp + 64);
        af[2] = *(const half8*)(rowp + 128);
        af[3] = *(const half8*)(rowp + 192);
#pragma unroll
        for (int kk = 0; kk < 4; ++kk) {
            half8 v = af[kk];
#pragma unroll
            for (int j = 0; j < 8; ++j) v[j] = (v[j] > (_Float16)0.f) ? v[j] : (_Float16)0.f;
            af[kk] = v;
        }
        float tsc = 0.f, tcs = 0.f;
#pragma unroll
        for (int ft = 0; ft < 8; ++ft) {
            float4v c = {0.f, 0.f, 0.f, 0.f};
            c = __builtin_amdgcn_mfma_f32_16x16x32_f16(af[0], bf[ft][0], c, 0, 0, 0);
            c = __builtin_amdgcn_mfma_f32_16x16x32_f16(af[1], bf[ft][1], c, 0, 0, 0);
            c = __builtin_amdgcn_mfma_f32_16x16x32_f16(af[2], bf[ft][2], c, 0, 0, 0);
            c = __builtin_amdgcn_mfma_f32_16x16x32_f16(af[3], bf[ft][3], c, 0, 0, 0);
#pragma unroll
            for (int r = 0; r < 4; ++r) {
                float y = c[r] + kbv[ft];
                float e = __expf(2.f * y);
                tsc += qv[ft] * (1.f - 2.f * __builtin_amdgcn_rcpf(e + 1.f));
            }
        }
        {
            float4v c = {0.f, 0.f, 0.f, 0.f};
            c = __builtin_amdgcn_mfma_f32_16x16x32_f16(af[0], bf[8][0], c, 0, 0, 0);
            c = __builtin_amdgcn_mfma_f32_16x16x32_f16(af[1], bf[8][1], c, 0, 0, 0);
            c = __builtin_amdgcn_mfma_f32_16x16x32_f16(af[2], bf[8][2], c, 0, 0, 0);
            c = __builtin_amdgcn_mfma_f32_16x16x32_f16(af[3], bf[8][3], c, 0, 0, 0);
            tcs = c[0] + c[1] + c[2] + c[3];
        }
        if (m == 0)      { sc[0] += tsc; cs[0] += tcs; }
        else if (m == 1) { sc[1] += tsc; cs[1] += tcs; }
        else if (m == 2) { sc[2] += tsc; cs[2] += tcs; }
        else             { sc[3] += tsc; cs[3] += tcs; }
    }

#pragma unroll
    for (int m = 0; m < 4; ++m) {
        float s = sc[m];
#pragma unroll
        for (int off = 1; off < 64; off <<= 1) s += __shfl_xor(s, off);
        if (lane == 0 && s != 0.f) atomicAdd(&redv[m], s);
        float v = cs[m];
        v += __shfl_xor(v, 16);
        v += __shfl_xor(v, 32);
        if (hi == 0 && fi < 2 && v != 0.f) atomicAdd(&redv[4 + 2 * m + fi], v);
    }
    __syncthreads();
    if (tid < 4)              atomicAdd(&score[tid], redv[tid]);
    if (tid >= 4 && tid < 12) atomicAdd(&cs2[tid - 4], redv[tid]);
}

// ---------------------------------------------------------------------------
// Stage 5: semantic softmax + classifier + sigmoid. One thread.
// ---------------------------------------------------------------------------
__global__ void final_kernel(const float* __restrict__ cs2,
                             const float* __restrict__ score,
                             const float* __restrict__ lb,
                             float* __restrict__ out)
{
    float s0 = score[0] / (float)N0;
    float s1 = score[1] / (float)N0;
    float s2 = score[2] / (float)N1;
    float s3 = score[3] / (float)N1;
    float m0 = fmaxf(s0, s1);
    float e0 = expf(s0 - m0), e1 = expf(s1 - m0);
    float a0 = e0 / (e0 + e1), a1 = e1 / (e0 + e1);
    float m1 = fmaxf(s2, s3);
    float e2 = expf(s2 - m1), e3 = expf(s3 - m1);
    float a2 = e2 / (e2 + e3), a3 = e3 / (e2 + e3);
    float z0 = a0 * cs2[0] + a1 * cs2[2] + a2 * cs2[4] + a3 * cs2[6] + lb[0];
    float z1 = a0 * cs2[1] + a1 * cs2[3] + a2 * cs2[5] + a3 * cs2[7] + lb[1];
    out[0] = 1.f / (1.f + expf(-z0));
    out[1] = 1.f / (1.f + expf(-z1));
}

extern "C" void kernel_launch(void* const* d_in, const int* in_sizes, int n_in,
                              void* d_out, int out_size, void* d_ws, size_t ws_size,
                              hipStream_t stream)
{
    const float* x0  = (const float*)d_in[0];
    const float* x1  = (const float*)d_in[1];
    const float* x2  = (const float*)d_in[2];
    const int* ei00  = (const int*)d_in[3];
    const int* ei11  = (const int*)d_in[4];
    const int* ei10  = (const int*)d_in[5];
    const int* ei21  = (const int*)d_in[6];
    const float* W0  = (const float*)d_in[7];  const float* b0 = (const float*)d_in[8];
    const float* W1  = (const float*)d_in[9];  const float* b1 = (const float*)d_in[10];
    const float* W2  = (const float*)d_in[11]; const float* b2 = (const float*)d_in[12];
    const float* as00 = (const float*)d_in[13]; const float* ad00 = (const float*)d_in[14];
    const float* as11 = (const float*)d_in[15]; const float* ad11 = (const float*)d_in[16];
    const float* as10 = (const float*)d_in[17]; const float* ad10 = (const float*)d_in[18];
    const float* as21 = (const float*)d_in[19]; const float* ad21 = (const float*)d_in[20];
    const float* kw  = (const float*)d_in[21]; const float* kb  = (const float*)d_in[22];
    const float* q   = (const float*)d_in[23];
    const float* lw  = (const float*)d_in[24]; const float* lb  = (const float*)d_in[25];
    float* out = (float*)d_out;

    char* p = (char*)d_ws;
    auto alloc = [&](size_t bytes) {
        char* r = p;
        p += (bytes + 255) & ~(size_t)255;
        return r;
    };
    __half2* h0 = (__half2*)alloc((size_t)N0 * 256);   // [N][64] half2 = [N][128] f16
    __half2* h1 = (__half2*)alloc((size_t)N1 * 256);
    __half2* h2 = (__half2*)alloc((size_t)N2 * 256);
    float* o_as00 = (float*)alloc((size_t)N0 * 32);
    float* o_ad00 = (float*)alloc((size_t)N0 * 32);
    float* o_as11 = (float*)alloc((size_t)N1 * 32);
    float* o_ad11 = (float*)alloc((size_t)N1 * 32);
    float* o_as10 = (float*)alloc((size_t)N1 * 32);   // src of b10 = cell1
    float* o_ad10 = (float*)alloc((size_t)N0 * 32);   // dst of b10 = cell0
    float* o_as21 = (float*)alloc((size_t)N2 * 32);   // src of b21 = cell2
    float* o_ad21 = (float*)alloc((size_t)N1 * 32);   // dst of b21 = cell1
    int* off    = (int*)alloc((size_t)ND * 4);
    int* cursor = (int*)alloc((size_t)ND * 4);
    int* part   = (int*)alloc((size_t)512 * 4);
    int* srcs   = (int*)alloc((size_t)EE * 4);
    __half2* agg = (__half2*)alloc((size_t)ND * 256);  // [u00|b10|u11|b21]
    // ---- zero region (contiguous) ----
    char* zstart = p;
    int* cnt = (int*)alloc((size_t)ND * 4);
    float* colsum2 = (float*)alloc(8 * 4);
    float* score   = (float*)alloc(4 * 4);
    size_t zbytes = (size_t)(p - zstart);

    (void)hipMemsetAsync(zstart, 0, zbytes, stream);

    // fused MFMA projection: blocks [0,148) cell0, [148,440) cell1, [440,512) cell2
    PT t0 = {x0, W0, b0, (_Float16*)h0,
             as00, ad00, ad10, nullptr,
             o_as00, o_ad00, o_ad10, nullptr,
             N0, 3125, 0, 148};
    PT t1 = {x1, W1, b1, (_Float16*)h1,
             as11, ad11, as10, ad21,
             o_as11, o_ad11, o_as10, o_ad21,
             N1, 6250, 148, 292};
    PT t2 = {x2, W2, b2, (_Float16*)h2,
             as21, nullptr, nullptr, nullptr,
             o_as21, nullptr, nullptr, nullptr,
             N2, 1563, 440, 72};
    proj_mfma<<<512, 256, 0, stream>>>(t0, t1, t2);

    // CSR build
    count_kernel<<<(EE + 255) / 256, 256, 0, stream>>>(ei00, ei10, ei11, ei21, cnt);
    scan1_kernel<<<NB, 256, 0, stream>>>(cnt, part);
    scan2_kernel<<<1, 256, 0, stream>>>(part);
    scan3_kernel<<<NB, 256, 0, stream>>>(cnt, part, off, cursor);
    fill_kernel<<<(EE + 255) / 256, 256, 0, stream>>>(ei00, ei10, ei11, ei21, cursor, srcs);

    // gather (segment softmax + weighted sum)
    gather_kernel<<<ND / 4, 256, 0, stream>>>(cnt, off, srcs, h0, h1, h2,
        o_as00, o_ad00, o_as10, o_ad10, o_as11, o_ad11, o_as21, o_ad21, agg);

    // fused semantic reduction over all 4 metapaths
    semantic_kernel<<<512, 256, 0, stream>>>((const _Float16*)agg, kw, lw, kb, q, colsum2, score);

    final_kernel<<<1, 1, 0, stream>>>(colsum2, score, lb, out);
}

// Round 6
// 328.593 us; speedup vs baseline: 2.9835x; 1.0101x over previous
//
#include <hip/hip_runtime.h>
#include <hip/hip_fp16.h>

#define N0 50000
#define N1 100000
#define N2 25000
#define E00 200000
#define E11 200000
#define E10 100000
#define E21 50000
#define EE  550000   // E00+E10+E11+E21 (concatenated edge space)
#define ND  300000   // 50000(u00)+50000(b10)+100000(u11)+100000(b21) dst slots
#define NB  293      // ceil(ND/1024) scan blocks
#define NT_ALL 18750 // ND/16 semantic tiles
#define HID 128
#define INC 64

typedef _Float16 half8 __attribute__((ext_vector_type(8)));
typedef float float4v __attribute__((ext_vector_type(4)));
typedef float floatx2 __attribute__((ext_vector_type(2)));

// ---------------------------------------------------------------------------
// Stage 1 (fused, MFMA): per node type, h = x @ W + b (fp8 e4m3, [N][128] B)
// and attention dots a_p = x @ (W·A_p) + b·A_p (fp32 [N][8]).
// mfma_f32_16x16x32_f16: A[m=lane&15][k=(lane>>4)*8+j]; B[k][n=lane&15];
// C: col=lane&15, row=(lane>>4)*4+reg.
// ---------------------------------------------------------------------------
struct PT {
    const float* x; const float* W; const float* bias; unsigned char* h;
    const float* av0; const float* av1; const float* av2; const float* av3;
    float* ao0; float* ao1; float* ao2; float* ao3;
    int N; int ntiles; int bstart; int nblocks;
};

#define WPAD 72   // halves; row stride 144 B (16B-aligned b128 frags)
#define HPAD 136  // halves; row stride 272 B (16B-aligned b128 reads)

__global__ __launch_bounds__(256) void proj_mfma(PT t0, PT t1, PT t2)
{
    __shared__ _Float16 WT[128 * WPAD];    // 18.4 KB: WT[f][g] = W[g][f]
    __shared__ _Float16 AdT[32 * WPAD];    // 4.6 KB: (W·A)^T [c][g]
    __shared__ _Float16 ht[4][16][HPAD];   // 17.4 KB: per-wave h tile (f16)
    const int tid = threadIdx.x;
    const int lane = tid & 63, wv = tid >> 6;
    const int fi = lane & 15, hi = lane >> 4;

    PT A = (blockIdx.x >= t2.bstart) ? t2 : (blockIdx.x >= t1.bstart) ? t1 : t0;

    for (int idx = tid; idx < 64 * 128; idx += 256) {
        int g = idx >> 7, f = idx & 127;
        WT[f * WPAD + g] = (_Float16)A.W[idx];
    }
    const float* avs[4] = {A.av0, A.av1, A.av2, A.av3};
    for (int idx = tid; idx < 32 * 64; idx += 256) {
        int c = idx & 31, g = idx >> 5;
        const float* av = avs[c >> 3];
        float v = 0.f;
        if (av) {
            int hh = c & 7;
#pragma unroll
            for (int d = 0; d < 16; ++d)
                v += A.W[g * 128 + hh * 16 + d] * av[hh * 16 + d];
        }
        AdT[c * WPAD + g] = (_Float16)v;
    }
    __syncthreads();

    // persistent B fragments (K=64 -> 2 k-blocks)
    half8 bfr[8][2], bd[2][2];
#pragma unroll
    for (int nt = 0; nt < 8; ++nt)
#pragma unroll
        for (int kb = 0; kb < 2; ++kb)
            bfr[nt][kb] = *(const half8*)&WT[(nt * 16 + fi) * WPAD + kb * 32 + hi * 8];
#pragma unroll
    for (int t = 0; t < 2; ++t)
#pragma unroll
        for (int kb = 0; kb < 2; ++kb)
            bd[t][kb] = *(const half8*)&AdT[(t * 16 + fi) * WPAD + kb * 32 + hi * 8];

    float bvv[8];
#pragma unroll
    for (int nt = 0; nt < 8; ++nt) bvv[nt] = A.bias[nt * 16 + fi];
    float bdc[2] = {0.f, 0.f};
    {
        int hh = fi & 7;
        const float* alo = (fi >= 8) ? A.av1 : A.av0;
        const float* ahi = (fi >= 8) ? A.av3 : A.av2;
#pragma unroll
        for (int d = 0; d < 16; ++d) {
            float bb = A.bias[hh * 16 + d];
            if (alo) bdc[0] += bb * alo[hh * 16 + d];
            if (ahi) bdc[1] += bb * ahi[hh * 16 + d];
        }
    }
    float* aolo = (fi >= 8) ? A.ao1 : A.ao0;
    float* aohi = (fi >= 8) ? A.ao3 : A.ao2;
    const bool has_hi = (A.av2 != nullptr) || (A.av3 != nullptr);

    const int stride = A.nblocks * 4;
    for (int t = (blockIdx.x - A.bstart) * 4 + wv; t < A.ntiles; t += stride) {
        const int base = t * 16;
        int rsrc = base + fi; if (rsrc >= A.N) rsrc = A.N - 1;
        const float* xp = A.x + (size_t)rsrc * 64 + hi * 8;
        float4 u0 = *(const float4*)(xp);
        float4 u1 = *(const float4*)(xp + 4);
        float4 u2 = *(const float4*)(xp + 32);
        float4 u3 = *(const float4*)(xp + 36);
        half8 a0, a1;
        a0[0] = (_Float16)u0.x; a0[1] = (_Float16)u0.y; a0[2] = (_Float16)u0.z; a0[3] = (_Float16)u0.w;
        a0[4] = (_Float16)u1.x; a0[5] = (_Float16)u1.y; a0[6] = (_Float16)u1.z; a0[7] = (_Float16)u1.w;
        a1[0] = (_Float16)u2.x; a1[1] = (_Float16)u2.y; a1[2] = (_Float16)u2.z; a1[3] = (_Float16)u2.w;
        a1[4] = (_Float16)u3.x; a1[5] = (_Float16)u3.y; a1[6] = (_Float16)u3.z; a1[7] = (_Float16)u3.w;

        float4v c[8];
#pragma unroll
        for (int nt = 0; nt < 8; ++nt) {
            float4v z = {0.f, 0.f, 0.f, 0.f};
            z = __builtin_amdgcn_mfma_f32_16x16x32_f16(a0, bfr[nt][0], z, 0, 0, 0);
            z = __builtin_amdgcn_mfma_f32_16x16x32_f16(a1, bfr[nt][1], z, 0, 0, 0);
            c[nt] = z;
        }
        float4v d0 = {0.f, 0.f, 0.f, 0.f};
        d0 = __builtin_amdgcn_mfma_f32_16x16x32_f16(a0, bd[0][0], d0, 0, 0, 0);
        d0 = __builtin_amdgcn_mfma_f32_16x16x32_f16(a1, bd[0][1], d0, 0, 0, 0);
        float4v d1 = {0.f, 0.f, 0.f, 0.f};
        if (has_hi) {
            d1 = __builtin_amdgcn_mfma_f32_16x16x32_f16(a0, bd[1][0], d1, 0, 0, 0);
            d1 = __builtin_amdgcn_mfma_f32_16x16x32_f16(a1, bd[1][1], d1, 0, 0, 0);
        }

        // h epilogue: C frags -> per-wave LDS tile -> fp8 coalesced stores
#pragma unroll
        for (int nt = 0; nt < 8; ++nt)
#pragma unroll
            for (int r = 0; r < 4; ++r)
                ht[wv][hi * 4 + r][nt * 16 + fi] = (_Float16)(c[nt][r] + bvv[nt]);
#pragma unroll
        for (int i = 0; i < 4; ++i) {
            int row = i * 4 + hi;
            int node = base + row;
            if (node < A.N) {
                half8 v = *(const half8*)&ht[wv][row][fi * 8];
                int pa = __builtin_amdgcn_cvt_pk_fp8_f32((float)v[0], (float)v[1], 0, false);
                pa = __builtin_amdgcn_cvt_pk_fp8_f32((float)v[2], (float)v[3], pa, true);
                int pb = __builtin_amdgcn_cvt_pk_fp8_f32((float)v[4], (float)v[5], 0, false);
                pb = __builtin_amdgcn_cvt_pk_fp8_f32((float)v[6], (float)v[7], pb, true);
                int2 o = {pa, pb};
                *(int2*)(A.h + (size_t)node * 128 + fi * 8) = o;
            }
        }
        if (aolo) {
#pragma unroll
            for (int r = 0; r < 4; ++r) {
                int node = base + hi * 4 + r;
                if (node < A.N) aolo[(size_t)node * 8 + (fi & 7)] = d0[r] + bdc[0];
            }
        }
        if (aohi) {
#pragma unroll
            for (int r = 0; r < 4; ++r) {
                int node = base + hi * 4 + r;
                if (node < A.N) aohi[(size_t)node * 8 + (fi & 7)] = d1[r] + bdc[1];
            }
        }
    }
}

// ---------------------------------------------------------------------------
// CSR build over the concatenated (edge-type, dst) slot space.
// ---------------------------------------------------------------------------
__device__ __forceinline__ void decode_edge(
    int e, const int* ei00, const int* ei10, const int* ei11, const int* ei21,
    int& src, int& slot)
{
    if (e < E00)                    { src = ei00[e];               slot = ei00[E00 + e]; }
    else if (e < E00 + E10)         { int i = e - E00;             src = ei10[i]; slot = 50000  + ei10[E10 + i]; }
    else if (e < E00 + E10 + E11)   { int i = e - E00 - E10;       src = ei11[i]; slot = 100000 + ei11[E11 + i]; }
    else                            { int i = e - E00 - E10 - E11; src = ei21[i]; slot = 200000 + ei21[E21 + i]; }
}

__global__ __launch_bounds__(256) void count_kernel(
    const int* __restrict__ ei00, const int* __restrict__ ei10,
    const int* __restrict__ ei11, const int* __restrict__ ei21,
    int* __restrict__ cnt)
{
    int e = blockIdx.x * 256 + threadIdx.x;
    if (e >= EE) return;
    int src, slot;
    decode_edge(e, ei00, ei10, ei11, ei21, src, slot);
    atomicAdd(&cnt[slot], 1);
}

__global__ __launch_bounds__(256) void scan1_kernel(
    const int* __restrict__ cnt, int* __restrict__ part)
{
    const int tid = threadIdx.x, b = blockIdx.x;
    int i0 = b * 1024 + tid * 4;
    int s = 0;
#pragma unroll
    for (int k = 0; k < 4; ++k) { int i = i0 + k; s += (i < ND) ? cnt[i] : 0; }
#pragma unroll
    for (int off = 1; off < 64; off <<= 1) s += __shfl_xor(s, off);
    __shared__ int wt[4];
    if ((tid & 63) == 0) wt[tid >> 6] = s;
    __syncthreads();
    if (tid == 0) part[b] = wt[0] + wt[1] + wt[2] + wt[3];
}

__global__ __launch_bounds__(256) void scan2_kernel(int* __restrict__ part)
{
    const int t = threadIdx.x;
    int p0 = (2 * t     < NB) ? part[2 * t]     : 0;
    int p1 = (2 * t + 1 < NB) ? part[2 * t + 1] : 0;
    int ps = p0 + p1;
    __shared__ int sd[256];
    sd[t] = ps; __syncthreads();
    for (int d = 1; d < 256; d <<= 1) {
        int v = (t >= d) ? sd[t - d] : 0;
        __syncthreads();
        sd[t] += v;
        __syncthreads();
    }
    int exc = sd[t] - ps;
    if (2 * t     < NB) part[2 * t]     = exc;
    if (2 * t + 1 < NB) part[2 * t + 1] = exc + p0;
}

__global__ __launch_bounds__(256) void scan3_kernel(
    const int* __restrict__ cnt, const int* __restrict__ part,
    int* __restrict__ off, int* __restrict__ cursor)
{
    const int tid = threadIdx.x, b = blockIdx.x;
    const int lane = tid & 63, wv = tid >> 6;
    int i0 = b * 1024 + tid * 4;
    int v[4];
#pragma unroll
    for (int k = 0; k < 4; ++k) { int i = i0 + k; v[k] = (i < ND) ? cnt[i] : 0; }
    int ts = v[0] + v[1] + v[2] + v[3];
    int inc = ts;
#pragma unroll
    for (int d = 1; d < 64; d <<= 1) {
        int u = __shfl_up(inc, d);
        if (lane >= d) inc += u;
    }
    int wexc = inc - ts;
    __shared__ int wt[4];
    if (lane == 63) wt[wv] = inc;
    __syncthreads();
    int wbase = 0;
    for (int w = 0; w < wv; ++w) wbase += wt[w];
    int base = part[b] + wbase + wexc;
    int pre = 0;
#pragma unroll
    for (int k = 0; k < 4; ++k) {
        int i = i0 + k;
        if (i < ND) { off[i] = base + pre; cursor[i] = base + pre; }
        pre += v[k];
    }
}

__global__ __launch_bounds__(256) void fill_kernel(
    const int* __restrict__ ei00, const int* __restrict__ ei10,
    const int* __restrict__ ei11, const int* __restrict__ ei21,
    int* __restrict__ cursor, int* __restrict__ srcs)
{
    int e = blockIdx.x * 256 + threadIdx.x;
    if (e >= EE) return;
    int src, slot;
    decode_edge(e, ei00, ei10, ei11, ei21, src, slot);
    int pos = atomicAdd(&cursor[slot], 1);
    srcs[pos] = src;
}

// ---------------------------------------------------------------------------
// Gather: one wave per dst slot. Lane l = feature pair (2l,2l+1), head l>>3.
// h is fp8 e4m3 ([N][128] B, lane reads ushort = 2 fp8). Online softmax,
// relu applied here, agg stored as fp8 ([slot][128] B) — written exactly once.
// ---------------------------------------------------------------------------
__global__ __launch_bounds__(256) void gather_kernel(
    const int* __restrict__ cnt, const int* __restrict__ off,
    const int* __restrict__ srcs,
    const unsigned short* __restrict__ h0, const unsigned short* __restrict__ h1,
    const unsigned short* __restrict__ h2,
    const float* __restrict__ as00, const float* __restrict__ ad00,
    const float* __restrict__ as10, const float* __restrict__ ad10,
    const float* __restrict__ as11, const float* __restrict__ ad11,
    const float* __restrict__ as21, const float* __restrict__ ad21,
    unsigned short* __restrict__ agg)
{
    int gid = blockIdx.x * 256 + threadIdx.x;
    int slot = gid >> 6, l = gid & 63;
    if (slot >= ND) return;
    const unsigned short* hs; const float* asp; const float* adp; int d;
    if (slot < 50000)       { hs = h0; asp = as00; adp = ad00; d = slot; }
    else if (slot < 100000) { hs = h1; asp = as10; adp = ad10; d = slot - 50000; }
    else if (slot < 200000) { hs = h1; asp = as11; adp = ad11; d = slot - 100000; }
    else                    { hs = h2; asp = as21; adp = ad21; d = slot - 200000; }
    const int h = l >> 3;
    const float ad = adp[d * 8 + h];
    const int deg = cnt[slot], st = off[slot];

    float ax = 0.f, ay = 0.f, sw = 0.f;
    int i = 0;
    for (; i + 2 <= deg; i += 2) {
        // load phase (independent) ...
        int s0 = srcs[st + i], s1 = srcs[st + i + 1];
        float aa0 = asp[s0 * 8 + h], aa1 = asp[s1 * 8 + h];
        unsigned short u0 = hs[(size_t)s0 * 64 + l];
        unsigned short u1 = hs[(size_t)s1 * 64 + l];
        // ... use phase
        float v0 = aa0 + ad; v0 = v0 > 0.f ? v0 : 0.2f * v0;
        float v1 = aa1 + ad; v1 = v1 > 0.f ? v1 : 0.2f * v1;
        float w0 = __expf(v0), w1 = __expf(v1);
        floatx2 f0 = __builtin_amdgcn_cvt_pk_f32_fp8((int)u0, false);
        floatx2 f1 = __builtin_amdgcn_cvt_pk_f32_fp8((int)u1, false);
        ax += w0 * f0.x + w1 * f1.x;
        ay += w0 * f0.y + w1 * f1.y;
        sw += w0 + w1;
    }
    if (i < deg) {
        int s0 = srcs[st + i];
        float aa0 = asp[s0 * 8 + h];
        unsigned short u0 = hs[(size_t)s0 * 64 + l];
        float v0 = aa0 + ad; v0 = v0 > 0.f ? v0 : 0.2f * v0;
        float w0 = __expf(v0);
        floatx2 f0 = __builtin_amdgcn_cvt_pk_f32_fp8((int)u0, false);
        ax += w0 * f0.x;
        ay += w0 * f0.y;
        sw += w0;
    }

    float rr = __builtin_amdgcn_rcpf(sw + 1e-16f);
    float rx = fmaxf(ax * rr, 0.f), ry = fmaxf(ay * rr, 0.f);  // relu here
    int pk = __builtin_amdgcn_cvt_pk_fp8_f32(rx, ry, 0, false);
    agg[(size_t)slot * 64 + l] = (unsigned short)pk;
}

// ---------------------------------------------------------------------------
// Stage 4 (fused, fp8 MFMA over all 4 metapaths): Y = agg_relu @ [k_w | lin_w].
// mfma_f32_16x16x32_fp8_fp8: A = 8 fp8/lane (same (m,k) map as f16 shape),
// B[k][n=lane&15]; C: col=lane&15, row=(lane>>4)*4+reg.
// metapath of tile t: 3=t>=12500, 2=t>=6250, 1=t>=3125, else 0 (u00,b10,u11,b21).
// ---------------------------------------------------------------------------
#define KSTRB 136
__global__ __launch_bounds__(256, 2) void semantic_kernel(
    const unsigned char* __restrict__ agg,
    const float* __restrict__ kw, const float* __restrict__ lw,
    const float* __restrict__ kb, const float* __restrict__ q,
    float* __restrict__ cs2, float* __restrict__ score)
{
    __shared__ unsigned char kwT[144 * KSTRB];   // 19.6 KB fp8, f-major
    __shared__ float redv[12];
    const int tid = threadIdx.x;
    const int lane = tid & 63, wv = tid >> 6;
    const int fi = lane & 15, hi = lane >> 4;

    for (int idx = tid; idx < 128 * 128; idx += 256) {
        int g = idx >> 7, f = idx & 127;
        int r = __builtin_amdgcn_cvt_pk_fp8_f32(kw[idx], 0.f, 0, false);
        kwT[f * KSTRB + g] = (unsigned char)r;
    }
    for (int idx = tid; idx < 16 * 128; idx += 256) {
        int f2 = idx >> 7, g = idx & 127;
        float v = (f2 < 2) ? lw[g * 2 + f2] : 0.f;
        int r = __builtin_amdgcn_cvt_pk_fp8_f32(v, 0.f, 0, false);
        kwT[(128 + f2) * KSTRB + g] = (unsigned char)r;
    }
    if (tid < 12) redv[tid] = 0.f;
    __syncthreads();

    long bf[9][4];
#pragma unroll
    for (int ft = 0; ft < 9; ++ft)
#pragma unroll
        for (int kk = 0; kk < 4; ++kk)
            bf[ft][kk] = *(const long*)&kwT[(ft * 16 + fi) * KSTRB + kk * 32 + hi * 8];

    float qv[8], kbv[8];
#pragma unroll
    for (int ft = 0; ft < 8; ++ft) {
        qv[ft] = q[ft * 16 + fi];
        kbv[ft] = kb[ft * 16 + fi];
    }

    float sc[4] = {0.f, 0.f, 0.f, 0.f};
    float cs[4] = {0.f, 0.f, 0.f, 0.f};
    const int nw = gridDim.x * 4;
    for (int t = blockIdx.x * 4 + wv; t < NT_ALL; t += nw) {
        const int m = (t >= 12500) ? 3 : (t >= 6250) ? 2 : (t >= 3125) ? 1 : 0;
        const unsigned char* rowp = agg + ((size_t)(t * 16 + fi) * 128 + hi * 8);
        long af[4];
        af[0] = *(const long*)(rowp);
        af[1] = *(const long*)(rowp + 32);
        af[2] = *(const long*)(rowp + 64);
        af[3] = *(const long*)(rowp + 96);
        float tsc = 0.f, tcs = 0.f;
#pragma unroll
        for (int ft = 0; ft < 8; ++ft) {
            float4v c = {0.f, 0.f, 0.f, 0.f};
            c = __builtin_amdgcn_mfma_f32_16x16x32_fp8_fp8(af[0], bf[ft][0], c, 0, 0, 0);
            c = __builtin_amdgcn_mfma_f32_16x16x32_fp8_fp8(af[1], bf[ft][1], c, 0, 0, 0);
            c = __builtin_amdgcn_mfma_f32_16x16x32_fp8_fp8(af[2], bf[ft][2], c, 0, 0, 0);
            c = __builtin_amdgcn_mfma_f32_16x16x32_fp8_fp8(af[3], bf[ft][3], c, 0, 0, 0);
#pragma unroll
            for (int r = 0; r < 4; ++r) {
                float y = c[r] + kbv[ft];
                float e = __expf(2.f * y);
                tsc += qv[ft] * (1.f - 2.f * __builtin_amdgcn_rcpf(e + 1.f));
            }
        }
        {
            float4v c = {0.f, 0.f, 0.f, 0.f};
            c = __builtin_amdgcn_mfma_f32_16x16x32_fp8_fp8(af[0], bf[8][0], c, 0, 0, 0);
            c = __builtin_amdgcn_mfma_f32_16x16x32_fp8_fp8(af[1], bf[8][1], c, 0, 0, 0);
            c = __builtin_amdgcn_mfma_f32_16x16x32_fp8_fp8(af[2], bf[8][2], c, 0, 0, 0);
            c = __builtin_amdgcn_mfma_f32_16x16x32_fp8_fp8(af[3], bf[8][3], c, 0, 0, 0);
            tcs = c[0] + c[1] + c[2] + c[3];
        }
        if (m == 0)      { sc[0] += tsc; cs[0] += tcs; }
        else if (m == 1) { sc[1] += tsc; cs[1] += tcs; }
        else if (m == 2) { sc[2] += tsc; cs[2] += tcs; }
        else             { sc[3] += tsc; cs[3] += tcs; }
    }

#pragma unroll
    for (int m = 0; m < 4; ++m) {
        float s = sc[m];
#pragma unroll
        for (int off = 1; off < 64; off <<= 1) s += __shfl_xor(s, off);
        if (lane == 0 && s != 0.f) atomicAdd(&redv[m], s);
        float v = cs[m];
        v += __shfl_xor(v, 16);
        v += __shfl_xor(v, 32);
        if (hi == 0 && fi < 2 && v != 0.f) atomicAdd(&redv[4 + 2 * m + fi], v);
    }
    __syncthreads();
    if (tid < 4)              atomicAdd(&score[tid], redv[tid]);
    if (tid >= 4 && tid < 12) atomicAdd(&cs2[tid - 4], redv[tid]);
}

// ---------------------------------------------------------------------------
// Stage 5: semantic softmax + classifier + sigmoid. One thread.
// ---------------------------------------------------------------------------
__global__ void final_kernel(const float* __restrict__ cs2,
                             const float* __restrict__ score,
                             const float* __restrict__ lb,
                             float* __restrict__ out)
{
    float s0 = score[0] / (float)N0;
    float s1 = score[1] / (float)N0;
    float s2 = score[2] / (float)N1;
    float s3 = score[3] / (float)N1;
    float m0 = fmaxf(s0, s1);
    float e0 = expf(s0 - m0), e1 = expf(s1 - m0);
    float a0 = e0 / (e0 + e1), a1 = e1 / (e0 + e1);
    float m1 = fmaxf(s2, s3);
    float e2 = expf(s2 - m1), e3 = expf(s3 - m1);
    float a2 = e2 / (e2 + e3), a3 = e3 / (e2 + e3);
    float z0 = a0 * cs2[0] + a1 * cs2[2] + a2 * cs2[4] + a3 * cs2[6] + lb[0];
    float z1 = a0 * cs2[1] + a1 * cs2[3] + a2 * cs2[5] + a3 * cs2[7] + lb[1];
    out[0] = 1.f / (1.f + expf(-z0));
    out[1] = 1.f / (1.f + expf(-z1));
}

extern "C" void kernel_launch(void* const* d_in, const int* in_sizes, int n_in,
                              void* d_out, int out_size, void* d_ws, size_t ws_size,
                              hipStream_t stream)
{
    const float* x0  = (const float*)d_in[0];
    const float* x1  = (const float*)d_in[1];
    const float* x2  = (const float*)d_in[2];
    const int* ei00  = (const int*)d_in[3];
    const int* ei11  = (const int*)d_in[4];
    const int* ei10  = (const int*)d_in[5];
    const int* ei21  = (const int*)d_in[6];
    const float* W0  = (const float*)d_in[7];  const float* b0 = (const float*)d_in[8];
    const float* W1  = (const float*)d_in[9];  const float* b1 = (const float*)d_in[10];
    const float* W2  = (const float*)d_in[11]; const float* b2 = (const float*)d_in[12];
    const float* as00 = (const float*)d_in[13]; const float* ad00 = (const float*)d_in[14];
    const float* as11 = (const float*)d_in[15]; const float* ad11 = (const float*)d_in[16];
    const float* as10 = (const float*)d_in[17]; const float* ad10 = (const float*)d_in[18];
    const float* as21 = (const float*)d_in[19]; const float* ad21 = (const float*)d_in[20];
    const float* kw  = (const float*)d_in[21]; const float* kb  = (const float*)d_in[22];
    const float* q   = (const float*)d_in[23];
    const float* lw  = (const float*)d_in[24]; const float* lb  = (const float*)d_in[25];
    float* out = (float*)d_out;

    char* p = (char*)d_ws;
    auto alloc = [&](size_t bytes) {
        char* r = p;
        p += (bytes + 255) & ~(size_t)255;
        return r;
    };
    unsigned char* h0 = (unsigned char*)alloc((size_t)N0 * 128);   // fp8 [N][128]
    unsigned char* h1 = (unsigned char*)alloc((size_t)N1 * 128);
    unsigned char* h2 = (unsigned char*)alloc((size_t)N2 * 128);
    float* o_as00 = (float*)alloc((size_t)N0 * 32);
    float* o_ad00 = (float*)alloc((size_t)N0 * 32);
    float* o_as11 = (float*)alloc((size_t)N1 * 32);
    float* o_ad11 = (float*)alloc((size_t)N1 * 32);
    float* o_as10 = (float*)alloc((size_t)N1 * 32);   // src of b10 = cell1
    float* o_ad10 = (float*)alloc((size_t)N0 * 32);   // dst of b10 = cell0
    float* o_as21 = (float*)alloc((size_t)N2 * 32);   // src of b21 = cell2
    float* o_ad21 = (float*)alloc((size_t)N1 * 32);   // dst of b21 = cell1
    int* off    = (int*)alloc((size_t)ND * 4);
    int* cursor = (int*)alloc((size_t)ND * 4);
    int* part   = (int*)alloc((size_t)512 * 4);
    int* srcs   = (int*)alloc((size_t)EE * 4);
    unsigned char* agg = (unsigned char*)alloc((size_t)ND * 128);  // fp8 [u00|b10|u11|b21]
    // ---- zero region (contiguous) ----
    char* zstart = p;
    int* cnt = (int*)alloc((size_t)ND * 4);
    float* colsum2 = (float*)alloc(8 * 4);
    float* score   = (float*)alloc(4 * 4);
    size_t zbytes = (size_t)(p - zstart);

    (void)hipMemsetAsync(zstart, 0, zbytes, stream);

    // fused MFMA projection: blocks [0,148) cell0, [148,440) cell1, [440,512) cell2
    PT t0 = {x0, W0, b0, h0,
             as00, ad00, ad10, nullptr,
             o_as00, o_ad00, o_ad10, nullptr,
             N0, 3125, 0, 148};
    PT t1 = {x1, W1, b1, h1,
             as11, ad11, as10, ad21,
             o_as11, o_ad11, o_as10, o_ad21,
             N1, 6250, 148, 292};
    PT t2 = {x2, W2, b2, h2,
             as21, nullptr, nullptr, nullptr,
             o_as21, nullptr, nullptr, nullptr,
             N2, 1563, 440, 72};
    proj_mfma<<<512, 256, 0, stream>>>(t0, t1, t2);

    // CSR build
    count_kernel<<<(EE + 255) / 256, 256, 0, stream>>>(ei00, ei10, ei11, ei21, cnt);
    scan1_kernel<<<NB, 256, 0, stream>>>(cnt, part);
    scan2_kernel<<<1, 256, 0, stream>>>(part);
    scan3_kernel<<<NB, 256, 0, stream>>>(cnt, part, off, cursor);
    fill_kernel<<<(EE + 255) / 256, 256, 0, stream>>>(ei00, ei10, ei11, ei21, cursor, srcs);

    // gather (segment softmax + weighted sum + relu, fp8 out)
    gather_kernel<<<ND / 4, 256, 0, stream>>>(cnt, off, srcs,
        (const unsigned short*)h0, (const unsigned short*)h1, (const unsigned short*)h2,
        o_as00, o_ad00, o_as10, o_ad10, o_as11, o_ad11, o_as21, o_ad21,
        (unsigned short*)agg);

    // fused semantic reduction over all 4 metapaths (fp8 MFMA)
    semantic_kernel<<<512, 256, 0, stream>>>(agg, kw, lw, kb, q, colsum2, score);

    final_kernel<<<1, 1, 0, stream>>>(colsum2, score, lb, out);
}

// Round 7
// 303.498 us; speedup vs baseline: 3.2302x; 1.0827x over previous
//
#include <hip/hip_runtime.h>
#include <hip/hip_fp16.h>

#define N0 50000
#define N1 100000
#define N2 25000
#define E00 200000
#define E11 200000
#define E10 100000
#define E21 50000
#define EE  550000   // E00+E10+E11+E21 (concatenated edge space)
#define ND  300000   // 50000(u00)+50000(b10)+100000(u11)+100000(b21) dst slots
#define NB  293      // ceil(ND/1024) scan blocks
#define NT_ALL 18750 // ND/16 semantic tiles
#define HID 128
#define INC 64

typedef _Float16 half8 __attribute__((ext_vector_type(8)));
typedef float float4v __attribute__((ext_vector_type(4)));
typedef float floatx2 __attribute__((ext_vector_type(2)));

// ---------------------------------------------------------------------------
// Stage 1 (fused, MFMA): per node type, h = x @ W + b (fp8 e4m3, [N][128] B)
// and attention dots a_p = x @ (W·A_p) + b·A_p (fp32 [N][8]).
// mfma_f32_16x16x32_f16: A[m=lane&15][k=(lane>>4)*8+j]; B[k][n=lane&15];
// C: col=lane&15, row=(lane>>4)*4+reg.
// ---------------------------------------------------------------------------
struct PT {
    const float* x; const float* W; const float* bias; unsigned char* h;
    const float* av0; const float* av1; const float* av2; const float* av3;
    float* ao0; float* ao1; float* ao2; float* ao3;
    int N; int ntiles; int bstart; int nblocks;
};

#define WPAD 72   // halves; row stride 144 B (16B-aligned b128 frags)
#define HPAD 136  // halves; row stride 272 B (16B-aligned b128 reads)

__global__ __launch_bounds__(256) void proj_mfma(PT t0, PT t1, PT t2)
{
    __shared__ _Float16 WT[128 * WPAD];    // 18.4 KB: WT[f][g] = W[g][f]
    __shared__ _Float16 AdT[32 * WPAD];    // 4.6 KB: (W·A)^T [c][g]
    __shared__ _Float16 ht[4][16][HPAD];   // 17.4 KB: per-wave h tile (f16)
    const int tid = threadIdx.x;
    const int lane = tid & 63, wv = tid >> 6;
    const int fi = lane & 15, hi = lane >> 4;

    PT A = (blockIdx.x >= t2.bstart) ? t2 : (blockIdx.x >= t1.bstart) ? t1 : t0;

    for (int idx = tid; idx < 64 * 128; idx += 256) {
        int g = idx >> 7, f = idx & 127;
        WT[f * WPAD + g] = (_Float16)A.W[idx];
    }
    __syncthreads();
    const float* avs[4] = {A.av0, A.av1, A.av2, A.av3};
    for (int idx = tid; idx < 32 * 64; idx += 256) {
        int c = idx & 31, g = idx >> 5;
        const float* av = avs[c >> 3];
        float v = 0.f;
        if (av) {
            int hh = c & 7;
#pragma unroll
            for (int d = 0; d < 16; ++d)
                v += (float)WT[(hh * 16 + d) * WPAD + g] * av[hh * 16 + d];
        }
        AdT[c * WPAD + g] = (_Float16)v;
    }
    __syncthreads();

    // persistent B fragments (K=64 -> 2 k-blocks)
    half8 bfr[8][2], bd[2][2];
#pragma unroll
    for (int nt = 0; nt < 8; ++nt)
#pragma unroll
        for (int kb = 0; kb < 2; ++kb)
            bfr[nt][kb] = *(const half8*)&WT[(nt * 16 + fi) * WPAD + kb * 32 + hi * 8];
#pragma unroll
    for (int t = 0; t < 2; ++t)
#pragma unroll
        for (int kb = 0; kb < 2; ++kb)
            bd[t][kb] = *(const half8*)&AdT[(t * 16 + fi) * WPAD + kb * 32 + hi * 8];

    float bvv[8];
#pragma unroll
    for (int nt = 0; nt < 8; ++nt) bvv[nt] = A.bias[nt * 16 + fi];
    float bdc[2] = {0.f, 0.f};
    {
        int hh = fi & 7;
        const float* alo = (fi >= 8) ? A.av1 : A.av0;
        const float* ahi = (fi >= 8) ? A.av3 : A.av2;
#pragma unroll
        for (int d = 0; d < 16; ++d) {
            float bb = A.bias[hh * 16 + d];
            if (alo) bdc[0] += bb * alo[hh * 16 + d];
            if (ahi) bdc[1] += bb * ahi[hh * 16 + d];
        }
    }
    float* aolo = (fi >= 8) ? A.ao1 : A.ao0;
    float* aohi = (fi >= 8) ? A.ao3 : A.ao2;
    const bool has_hi = (A.av2 != nullptr) || (A.av3 != nullptr);

    const int stride = A.nblocks * 4;
    for (int t = (blockIdx.x - A.bstart) * 4 + wv; t < A.ntiles; t += stride) {
        const int base = t * 16;
        int rsrc = base + fi; if (rsrc >= A.N) rsrc = A.N - 1;
        const float* xp = A.x + (size_t)rsrc * 64 + hi * 8;
        float4 u0 = *(const float4*)(xp);
        float4 u1 = *(const float4*)(xp + 4);
        float4 u2 = *(const float4*)(xp + 32);
        float4 u3 = *(const float4*)(xp + 36);
        half8 a0, a1;
        a0[0] = (_Float16)u0.x; a0[1] = (_Float16)u0.y; a0[2] = (_Float16)u0.z; a0[3] = (_Float16)u0.w;
        a0[4] = (_Float16)u1.x; a0[5] = (_Float16)u1.y; a0[6] = (_Float16)u1.z; a0[7] = (_Float16)u1.w;
        a1[0] = (_Float16)u2.x; a1[1] = (_Float16)u2.y; a1[2] = (_Float16)u2.z; a1[3] = (_Float16)u2.w;
        a1[4] = (_Float16)u3.x; a1[5] = (_Float16)u3.y; a1[6] = (_Float16)u3.z; a1[7] = (_Float16)u3.w;

        float4v c[8];
#pragma unroll
        for (int nt = 0; nt < 8; ++nt) {
            float4v z = {0.f, 0.f, 0.f, 0.f};
            z = __builtin_amdgcn_mfma_f32_16x16x32_f16(a0, bfr[nt][0], z, 0, 0, 0);
            z = __builtin_amdgcn_mfma_f32_16x16x32_f16(a1, bfr[nt][1], z, 0, 0, 0);
            c[nt] = z;
        }
        float4v d0 = {0.f, 0.f, 0.f, 0.f};
        d0 = __builtin_amdgcn_mfma_f32_16x16x32_f16(a0, bd[0][0], d0, 0, 0, 0);
        d0 = __builtin_amdgcn_mfma_f32_16x16x32_f16(a1, bd[0][1], d0, 0, 0, 0);
        float4v d1 = {0.f, 0.f, 0.f, 0.f};
        if (has_hi) {
            d1 = __builtin_amdgcn_mfma_f32_16x16x32_f16(a0, bd[1][0], d1, 0, 0, 0);
            d1 = __builtin_amdgcn_mfma_f32_16x16x32_f16(a1, bd[1][1], d1, 0, 0, 0);
        }

        // h epilogue: C frags -> per-wave LDS tile -> fp8 coalesced stores
#pragma unroll
        for (int nt = 0; nt < 8; ++nt)
#pragma unroll
            for (int r = 0; r < 4; ++r)
                ht[wv][hi * 4 + r][nt * 16 + fi] = (_Float16)(c[nt][r] + bvv[nt]);
#pragma unroll
        for (int i = 0; i < 4; ++i) {
            int row = i * 4 + hi;
            int node = base + row;
            if (node < A.N) {
                half8 v = *(const half8*)&ht[wv][row][fi * 8];
                int pa = __builtin_amdgcn_cvt_pk_fp8_f32((float)v[0], (float)v[1], 0, false);
                pa = __builtin_amdgcn_cvt_pk_fp8_f32((float)v[2], (float)v[3], pa, true);
                int pb = __builtin_amdgcn_cvt_pk_fp8_f32((float)v[4], (float)v[5], 0, false);
                pb = __builtin_amdgcn_cvt_pk_fp8_f32((float)v[6], (float)v[7], pb, true);
                int2 o = {pa, pb};
                *(int2*)(A.h + (size_t)node * 128 + fi * 8) = o;
            }
        }
        if (aolo) {
#pragma unroll
            for (int r = 0; r < 4; ++r) {
                int node = base + hi * 4 + r;
                if (node < A.N) aolo[(size_t)node * 8 + (fi & 7)] = d0[r] + bdc[0];
            }
        }
        if (aohi) {
#pragma unroll
            for (int r = 0; r < 4; ++r) {
                int node = base + hi * 4 + r;
                if (node < A.N) aohi[(size_t)node * 8 + (fi & 7)] = d1[r] + bdc[1];
            }
        }
    }
}

// ---------------------------------------------------------------------------
// CSR build over the concatenated (edge-type, dst) slot space.
// ---------------------------------------------------------------------------
__device__ __forceinline__ void decode_edge(
    int e, const int* ei00, const int* ei10, const int* ei11, const int* ei21,
    int& src, int& slot)
{
    if (e < E00)                    { src = ei00[e];               slot = ei00[E00 + e]; }
    else if (e < E00 + E10)         { int i = e - E00;             src = ei10[i]; slot = 50000  + ei10[E10 + i]; }
    else if (e < E00 + E10 + E11)   { int i = e - E00 - E10;       src = ei11[i]; slot = 100000 + ei11[E11 + i]; }
    else                            { int i = e - E00 - E10 - E11; src = ei21[i]; slot = 200000 + ei21[E21 + i]; }
}

__global__ __launch_bounds__(256) void count_kernel(
    const int* __restrict__ ei00, const int* __restrict__ ei10,
    const int* __restrict__ ei11, const int* __restrict__ ei21,
    int* __restrict__ cnt)
{
    int e = blockIdx.x * 256 + threadIdx.x;
    if (e >= EE) return;
    int src, slot;
    decode_edge(e, ei00, ei10, ei11, ei21, src, slot);
    atomicAdd(&cnt[slot], 1);
}

__global__ __launch_bounds__(256) void scan1_kernel(
    const int* __restrict__ cnt, int* __restrict__ part)
{
    const int tid = threadIdx.x, b = blockIdx.x;
    int i0 = b * 1024 + tid * 4;
    int s = 0;
#pragma unroll
    for (int k = 0; k < 4; ++k) { int i = i0 + k; s += (i < ND) ? cnt[i] : 0; }
#pragma unroll
    for (int off = 1; off < 64; off <<= 1) s += __shfl_xor(s, off);
    __shared__ int wt[4];
    if ((tid & 63) == 0) wt[tid >> 6] = s;
    __syncthreads();
    if (tid == 0) part[b] = wt[0] + wt[1] + wt[2] + wt[3];
}

__global__ __launch_bounds__(256) void scan2_kernel(int* __restrict__ part)
{
    const int t = threadIdx.x;
    int p0 = (2 * t     < NB) ? part[2 * t]     : 0;
    int p1 = (2 * t + 1 < NB) ? part[2 * t + 1] : 0;
    int ps = p0 + p1;
    __shared__ int sd[256];
    sd[t] = ps; __syncthreads();
    for (int d = 1; d < 256; d <<= 1) {
        int v = (t >= d) ? sd[t - d] : 0;
        __syncthreads();
        sd[t] += v;
        __syncthreads();
    }
    int exc = sd[t] - ps;
    if (2 * t     < NB) part[2 * t]     = exc;
    if (2 * t + 1 < NB) part[2 * t + 1] = exc + p0;
}

__global__ __launch_bounds__(256) void scan3_kernel(
    const int* __restrict__ cnt, const int* __restrict__ part,
    int* __restrict__ off, int* __restrict__ cursor)
{
    const int tid = threadIdx.x, b = blockIdx.x;
    const int lane = tid & 63, wv = tid >> 6;
    int i0 = b * 1024 + tid * 4;
    int v[4];
#pragma unroll
    for (int k = 0; k < 4; ++k) { int i = i0 + k; v[k] = (i < ND) ? cnt[i] : 0; }
    int ts = v[0] + v[1] + v[2] + v[3];
    int inc = ts;
#pragma unroll
    for (int d = 1; d < 64; d <<= 1) {
        int u = __shfl_up(inc, d);
        if (lane >= d) inc += u;
    }
    int wexc = inc - ts;
    __shared__ int wt[4];
    if (lane == 63) wt[wv] = inc;
    __syncthreads();
    int wbase = 0;
    for (int w = 0; w < wv; ++w) wbase += wt[w];
    int base = part[b] + wbase + wexc;
    int pre = 0;
#pragma unroll
    for (int k = 0; k < 4; ++k) {
        int i = i0 + k;
        if (i < ND) { off[i] = base + pre; cursor[i] = base + pre; }
        pre += v[k];
    }
}

// ---------------------------------------------------------------------------
// Fill: place src ids in CSR order AND precompute the 8 per-head softmax
// numerators w = exp(leaky_relu(a_s + a_d)) for each edge (f16x8, CSR order).
// Gather then never touches a_s/a_d and does no exp.
// ---------------------------------------------------------------------------
__global__ __launch_bounds__(256) void fill_kernel(
    const int* __restrict__ ei00, const int* __restrict__ ei10,
    const int* __restrict__ ei11, const int* __restrict__ ei21,
    const float* __restrict__ as00, const float* __restrict__ ad00,
    const float* __restrict__ as10, const float* __restrict__ ad10,
    const float* __restrict__ as11, const float* __restrict__ ad11,
    const float* __restrict__ as21, const float* __restrict__ ad21,
    int* __restrict__ cursor, int* __restrict__ srcs, _Float16* __restrict__ wgt)
{
    int e = blockIdx.x * 256 + threadIdx.x;
    if (e >= EE) return;
    int src, d, slot;
    const float* asp; const float* adp;
    if (e < E00) {
        src = ei00[e]; d = ei00[E00 + e]; slot = d; asp = as00; adp = ad00;
    } else if (e < E00 + E10) {
        int i = e - E00; src = ei10[i]; d = ei10[E10 + i]; slot = 50000 + d; asp = as10; adp = ad10;
    } else if (e < E00 + E10 + E11) {
        int i = e - E00 - E10; src = ei11[i]; d = ei11[E11 + i]; slot = 100000 + d; asp = as11; adp = ad11;
    } else {
        int i = e - E00 - E10 - E11; src = ei21[i]; d = ei21[E21 + i]; slot = 200000 + d; asp = as21; adp = ad21;
    }
    float4 sa0 = *(const float4*)(asp + (size_t)src * 8);
    float4 sa1 = *(const float4*)(asp + (size_t)src * 8 + 4);
    float4 da0 = *(const float4*)(adp + (size_t)d * 8);
    float4 da1 = *(const float4*)(adp + (size_t)d * 8 + 4);
    float vv[8] = {sa0.x + da0.x, sa0.y + da0.y, sa0.z + da0.z, sa0.w + da0.w,
                   sa1.x + da1.x, sa1.y + da1.y, sa1.z + da1.z, sa1.w + da1.w};
    half8 w;
#pragma unroll
    for (int h = 0; h < 8; ++h) {
        float v = vv[h];
        v = v > 0.f ? v : 0.2f * v;
        w[h] = (_Float16)__expf(v);
    }
    int pos = atomicAdd(&cursor[slot], 1);
    srcs[pos] = src;
    *(half8*)(wgt + (size_t)pos * 8) = w;
}

// ---------------------------------------------------------------------------
// Gather: 4 slots per wave, 16 lanes per slot; lane covers 8 fp8 features
// (one b64 load per edge), head = (lane&15)>>1. Weights read sequentially
// from the CSR-ordered wgt array. agg (fp8, relu'ed) written exactly once.
// ---------------------------------------------------------------------------
__global__ __launch_bounds__(256) void gather_kernel(
    const int* __restrict__ cnt, const int* __restrict__ off,
    const int* __restrict__ srcs, const _Float16* __restrict__ wgt,
    const unsigned char* __restrict__ h0, const unsigned char* __restrict__ h1,
    const unsigned char* __restrict__ h2,
    unsigned char* __restrict__ agg)
{
    const int gid = blockIdx.x * 256 + threadIdx.x;
    const int lane = gid & 63;
    const int grp = lane >> 4, lg = lane & 15;
    const int slot = (gid >> 6) * 4 + grp;          // grid sized so slot < ND
    const int head = lg >> 1;
    const unsigned char* hs = (slot < 50000) ? h0 : (slot < 200000) ? h1 : h2;
    const int deg = cnt[slot], st = off[slot];

    int degm = deg;
    degm = max(degm, __shfl_xor(degm, 16));
    degm = max(degm, __shfl_xor(degm, 32));

    float acc[8] = {0.f, 0.f, 0.f, 0.f, 0.f, 0.f, 0.f, 0.f};
    float sw = 0.f;
    int i = 0;
    for (; i + 2 <= degm; i += 2) {
        bool a0 = (i < deg), a1 = (i + 1 < deg);
        int s0 = 0, s1 = 0;
        if (a0) s0 = srcs[st + i];
        if (a1) s1 = srcs[st + i + 1];
        float w0 = 0.f, w1 = 0.f;
        unsigned long long v0 = 0, v1 = 0;
        if (a0) { w0 = (float)wgt[(size_t)(st + i) * 8 + head];
                  v0 = *(const unsigned long long*)(hs + (size_t)s0 * 128 + lg * 8); }
        if (a1) { w1 = (float)wgt[(size_t)(st + i + 1) * 8 + head];
                  v1 = *(const unsigned long long*)(hs + (size_t)s1 * 128 + lg * 8); }
        int l0 = (int)(v0 & 0xffffffffu), m0 = (int)(v0 >> 32);
        int l1 = (int)(v1 & 0xffffffffu), m1 = (int)(v1 >> 32);
        floatx2 f0a = __builtin_amdgcn_cvt_pk_f32_fp8(l0, false);
        floatx2 f0b = __builtin_amdgcn_cvt_pk_f32_fp8(l0, true);
        floatx2 f0c = __builtin_amdgcn_cvt_pk_f32_fp8(m0, false);
        floatx2 f0d = __builtin_amdgcn_cvt_pk_f32_fp8(m0, true);
        floatx2 f1a = __builtin_amdgcn_cvt_pk_f32_fp8(l1, false);
        floatx2 f1b = __builtin_amdgcn_cvt_pk_f32_fp8(l1, true);
        floatx2 f1c = __builtin_amdgcn_cvt_pk_f32_fp8(m1, false);
        floatx2 f1d = __builtin_amdgcn_cvt_pk_f32_fp8(m1, true);
        acc[0] += w0 * f0a.x + w1 * f1a.x;
        acc[1] += w0 * f0a.y + w1 * f1a.y;
        acc[2] += w0 * f0b.x + w1 * f1b.x;
        acc[3] += w0 * f0b.y + w1 * f1b.y;
        acc[4] += w0 * f0c.x + w1 * f1c.x;
        acc[5] += w0 * f0c.y + w1 * f1c.y;
        acc[6] += w0 * f0d.x + w1 * f1d.x;
        acc[7] += w0 * f0d.y + w1 * f1d.y;
        sw += w0 + w1;
    }
    if (i < degm) {
        bool a0 = (i < deg);
        int s0 = 0;
        if (a0) s0 = srcs[st + i];
        float w0 = 0.f;
        unsigned long long v0 = 0;
        if (a0) { w0 = (float)wgt[(size_t)(st + i) * 8 + head];
                  v0 = *(const unsigned long long*)(hs + (size_t)s0 * 128 + lg * 8); }
        int l0 = (int)(v0 & 0xffffffffu), m0 = (int)(v0 >> 32);
        floatx2 f0a = __builtin_amdgcn_cvt_pk_f32_fp8(l0, false);
        floatx2 f0b = __builtin_amdgcn_cvt_pk_f32_fp8(l0, true);
        floatx2 f0c = __builtin_amdgcn_cvt_pk_f32_fp8(m0, false);
        floatx2 f0d = __builtin_amdgcn_cvt_pk_f32_fp8(m0, true);
        acc[0] += w0 * f0a.x; acc[1] += w0 * f0a.y;
        acc[2] += w0 * f0b.x; acc[3] += w0 * f0b.y;
        acc[4] += w0 * f0c.x; acc[5] += w0 * f0c.y;
        acc[6] += w0 * f0d.x; acc[7] += w0 * f0d.y;
        sw += w0;
    }

    float rr = __builtin_amdgcn_rcpf(sw + 1e-16f);
    float r[8];
#pragma unroll
    for (int j = 0; j < 8; ++j) r[j] = fmaxf(acc[j] * rr, 0.f);   // relu here
    int pa = __builtin_amdgcn_cvt_pk_fp8_f32(r[0], r[1], 0, false);
    pa = __builtin_amdgcn_cvt_pk_fp8_f32(r[2], r[3], pa, true);
    int pb = __builtin_amdgcn_cvt_pk_fp8_f32(r[4], r[5], 0, false);
    pb = __builtin_amdgcn_cvt_pk_fp8_f32(r[6], r[7], pb, true);
    int2 o = {pa, pb};
    *(int2*)(agg + (size_t)slot * 128 + lg * 8) = o;
}

// ---------------------------------------------------------------------------
// Stage 4 (fused, fp8 MFMA over all 4 metapaths): Y = agg_relu @ [k_w | lin_w].
// metapath of tile t: 3=t>=12500, 2=t>=6250, 1=t>=3125, else 0 (u00,b10,u11,b21).
// ---------------------------------------------------------------------------
#define KSTRB 136
__global__ __launch_bounds__(256, 2) void semantic_kernel(
    const unsigned char* __restrict__ agg,
    const float* __restrict__ kw, const float* __restrict__ lw,
    const float* __restrict__ kb, const float* __restrict__ q,
    float* __restrict__ cs2, float* __restrict__ score)
{
    __shared__ unsigned char kwT[144 * KSTRB];   // 19.6 KB fp8, f-major
    __shared__ float redv[12];
    const int tid = threadIdx.x;
    const int lane = tid & 63, wv = tid >> 6;
    const int fi = lane & 15, hi = lane >> 4;

    for (int idx = tid; idx < 128 * 128; idx += 256) {
        int g = idx >> 7, f = idx & 127;
        int r = __builtin_amdgcn_cvt_pk_fp8_f32(kw[idx], 0.f, 0, false);
        kwT[f * KSTRB + g] = (unsigned char)r;
    }
    for (int idx = tid; idx < 16 * 128; idx += 256) {
        int f2 = idx >> 7, g = idx & 127;
        float v = (f2 < 2) ? lw[g * 2 + f2] : 0.f;
        int r = __builtin_amdgcn_cvt_pk_fp8_f32(v, 0.f, 0, false);
        kwT[(128 + f2) * KSTRB + g] = (unsigned char)r;
    }
    if (tid < 12) redv[tid] = 0.f;
    __syncthreads();

    long bf[9][4];
#pragma unroll
    for (int ft = 0; ft < 9; ++ft)
#pragma unroll
        for (int kk = 0; kk < 4; ++kk)
            bf[ft][kk] = *(const long*)&kwT[(ft * 16 + fi) * KSTRB + kk * 32 + hi * 8];

    float qv[8], kbv[8];
#pragma unroll
    for (int ft = 0; ft < 8; ++ft) {
        qv[ft] = q[ft * 16 + fi];
        kbv[ft] = kb[ft * 16 + fi];
    }

    float sc[4] = {0.f, 0.f, 0.f, 0.f};
    float cs[4] = {0.f, 0.f, 0.f, 0.f};
    const int nw = gridDim.x * 4;
    for (int t = blockIdx.x * 4 + wv; t < NT_ALL; t += nw) {
        const int m = (t >= 12500) ? 3 : (t >= 6250) ? 2 : (t >= 3125) ? 1 : 0;
        const unsigned char* rowp = agg + ((size_t)(t * 16 + fi) * 128 + hi * 8);
        long af[4];
        af[0] = *(const long*)(rowp);
        af[1] = *(const long*)(rowp + 32);
        af[2] = *(const long*)(rowp + 64);
        af[3] = *(const long*)(rowp + 96);
        float tsc = 0.f, tcs = 0.f;
#pragma unroll
        for (int ft = 0; ft < 8; ++ft) {
            float4v c = {0.f, 0.f, 0.f, 0.f};
            c = __builtin_amdgcn_mfma_f32_16x16x32_fp8_fp8(af[0], bf[ft][0], c, 0, 0, 0);
            c = __builtin_amdgcn_mfma_f32_16x16x32_fp8_fp8(af[1], bf[ft][1], c, 0, 0, 0);
            c = __builtin_amdgcn_mfma_f32_16x16x32_fp8_fp8(af[2], bf[ft][2], c, 0, 0, 0);
            c = __builtin_amdgcn_mfma_f32_16x16x32_fp8_fp8(af[3], bf[ft][3], c, 0, 0, 0);
#pragma unroll
            for (int r = 0; r < 4; ++r) {
                float y = c[r] + kbv[ft];
                float e = __expf(2.f * y);
                tsc += qv[ft] * (1.f - 2.f * __builtin_amdgcn_rcpf(e + 1.f));
            }
        }
        {
            float4v c = {0.f, 0.f, 0.f, 0.f};
            c = __builtin_amdgcn_mfma_f32_16x16x32_fp8_fp8(af[0], bf[8][0], c, 0, 0, 0);
            c = __builtin_amdgcn_mfma_f32_16x16x32_fp8_fp8(af[1], bf[8][1], c, 0, 0, 0);
            c = __builtin_amdgcn_mfma_f32_16x16x32_fp8_fp8(af[2], bf[8][2], c, 0, 0, 0);
            c = __builtin_amdgcn_mfma_f32_16x16x32_fp8_fp8(af[3], bf[8][3], c, 0, 0, 0);
            tcs = c[0] + c[1] + c[2] + c[3];
        }
        if (m == 0)      { sc[0] += tsc; cs[0] += tcs; }
        else if (m == 1) { sc[1] += tsc; cs[1] += tcs; }
        else if (m == 2) { sc[2] += tsc; cs[2] += tcs; }
        else             { sc[3] += tsc; cs[3] += tcs; }
    }

#pragma unroll
    for (int m = 0; m < 4; ++m) {
        float s = sc[m];
#pragma unroll
        for (int off = 1; off < 64; off <<= 1) s += __shfl_xor(s, off);
        if (lane == 0 && s != 0.f) atomicAdd(&redv[m], s);
        float v = cs[m];
        v += __shfl_xor(v, 16);
        v += __shfl_xor(v, 32);
        if (hi == 0 && fi < 2 && v != 0.f) atomicAdd(&redv[4 + 2 * m + fi], v);
    }
    __syncthreads();
    if (tid < 4)              atomicAdd(&score[tid], redv[tid]);
    if (tid >= 4 && tid < 12) atomicAdd(&cs2[tid - 4], redv[tid]);
}

// ---------------------------------------------------------------------------
// Stage 5: semantic softmax + classifier + sigmoid. One thread.
// ---------------------------------------------------------------------------
__global__ void final_kernel(const float* __restrict__ cs2,
                             const float* __restrict__ score,
                             const float* __restrict__ lb,
                             float* __restrict__ out)
{
    float s0 = score[0] / (float)N0;
    float s1 = score[1] / (float)N0;
    float s2 = score[2] / (float)N1;
    float s3 = score[3] / (float)N1;
    float m0 = fmaxf(s0, s1);
    float e0 = expf(s0 - m0), e1 = expf(s1 - m0);
    float a0 = e0 / (e0 + e1), a1 = e1 / (e0 + e1);
    float m1 = fmaxf(s2, s3);
    float e2 = expf(s2 - m1), e3 = expf(s3 - m1);
    float a2 = e2 / (e2 + e3), a3 = e3 / (e2 + e3);
    float z0 = a0 * cs2[0] + a1 * cs2[2] + a2 * cs2[4] + a3 * cs2[6] + lb[0];
    float z1 = a0 * cs2[1] + a1 * cs2[3] + a2 * cs2[5] + a3 * cs2[7] + lb[1];
    out[0] = 1.f / (1.f + expf(-z0));
    out[1] = 1.f / (1.f + expf(-z1));
}

extern "C" void kernel_launch(void* const* d_in, const int* in_sizes, int n_in,
                              void* d_out, int out_size, void* d_ws, size_t ws_size,
                              hipStream_t stream)
{
    const float* x0  = (const float*)d_in[0];
    const float* x1  = (const float*)d_in[1];
    const float* x2  = (const float*)d_in[2];
    const int* ei00  = (const int*)d_in[3];
    const int* ei11  = (const int*)d_in[4];
    const int* ei10  = (const int*)d_in[5];
    const int* ei21  = (const int*)d_in[6];
    const float* W0  = (const float*)d_in[7];  const float* b0 = (const float*)d_in[8];
    const float* W1  = (const float*)d_in[9];  const float* b1 = (const float*)d_in[10];
    const float* W2  = (const float*)d_in[11]; const float* b2 = (const float*)d_in[12];
    const float* as00 = (const float*)d_in[13]; const float* ad00 = (const float*)d_in[14];
    const float* as11 = (const float*)d_in[15]; const float* ad11 = (const float*)d_in[16];
    const float* as10 = (const float*)d_in[17]; const float* ad10 = (const float*)d_in[18];
    const float* as21 = (const float*)d_in[19]; const float* ad21 = (const float*)d_in[20];
    const float* kw  = (const float*)d_in[21]; const float* kb  = (const float*)d_in[22];
    const float* q   = (const float*)d_in[23];
    const float* lw  = (const float*)d_in[24]; const float* lb  = (const float*)d_in[25];
    float* out = (float*)d_out;

    char* p = (char*)d_ws;
    auto alloc = [&](size_t bytes) {
        char* r = p;
        p += (bytes + 255) & ~(size_t)255;
        return r;
    };
    unsigned char* h0 = (unsigned char*)alloc((size_t)N0 * 128);   // fp8 [N][128]
    unsigned char* h1 = (unsigned char*)alloc((size_t)N1 * 128);
    unsigned char* h2 = (unsigned char*)alloc((size_t)N2 * 128);
    float* o_as00 = (float*)alloc((size_t)N0 * 32);
    float* o_ad00 = (float*)alloc((size_t)N0 * 32);
    float* o_as11 = (float*)alloc((size_t)N1 * 32);
    float* o_ad11 = (float*)alloc((size_t)N1 * 32);
    float* o_as10 = (float*)alloc((size_t)N1 * 32);   // src of b10 = cell1
    float* o_ad10 = (float*)alloc((size_t)N0 * 32);   // dst of b10 = cell0
    float* o_as21 = (float*)alloc((size_t)N2 * 32);   // src of b21 = cell2
    float* o_ad21 = (float*)alloc((size_t)N1 * 32);   // dst of b21 = cell1
    int* off    = (int*)alloc((size_t)ND * 4);
    int* cursor = (int*)alloc((size_t)ND * 4);
    int* part   = (int*)alloc((size_t)512 * 4);
    int* srcs   = (int*)alloc((size_t)EE * 4);
    _Float16* wgt = (_Float16*)alloc((size_t)EE * 16);             // f16x8 per edge
    unsigned char* agg = (unsigned char*)alloc((size_t)ND * 128);  // fp8 [u00|b10|u11|b21]
    // ---- zero region (contiguous) ----
    char* zstart = p;
    int* cnt = (int*)alloc((size_t)ND * 4);
    float* colsum2 = (float*)alloc(8 * 4);
    float* score   = (float*)alloc(4 * 4);
    size_t zbytes = (size_t)(p - zstart);

    (void)hipMemsetAsync(zstart, 0, zbytes, stream);

    // fused MFMA projection: blocks [0,148) cell0, [148,440) cell1, [440,512) cell2
    PT t0 = {x0, W0, b0, h0,
             as00, ad00, ad10, nullptr,
             o_as00, o_ad00, o_ad10, nullptr,
             N0, 3125, 0, 148};
    PT t1 = {x1, W1, b1, h1,
             as11, ad11, as10, ad21,
             o_as11, o_ad11, o_as10, o_ad21,
             N1, 6250, 148, 292};
    PT t2 = {x2, W2, b2, h2,
             as21, nullptr, nullptr, nullptr,
             o_as21, nullptr, nullptr, nullptr,
             N2, 1563, 440, 72};
    proj_mfma<<<512, 256, 0, stream>>>(t0, t1, t2);

    // CSR build
    count_kernel<<<(EE + 255) / 256, 256, 0, stream>>>(ei00, ei10, ei11, ei21, cnt);
    scan1_kernel<<<NB, 256, 0, stream>>>(cnt, part);
    scan2_kernel<<<1, 256, 0, stream>>>(part);
    scan3_kernel<<<NB, 256, 0, stream>>>(cnt, part, off, cursor);
    fill_kernel<<<(EE + 255) / 256, 256, 0, stream>>>(ei00, ei10, ei11, ei21,
        o_as00, o_ad00, o_as10, o_ad10, o_as11, o_ad11, o_as21, o_ad21,
        cursor, srcs, wgt);

    // gather (4 slots/wave, CSR-ordered weights, fp8 h rows)
    gather_kernel<<<ND / 16, 256, 0, stream>>>(cnt, off, srcs, wgt, h0, h1, h2, agg);

    // fused semantic reduction over all 4 metapaths (fp8 MFMA)
    semantic_kernel<<<512, 256, 0, stream>>>(agg, kw, lw, kb, q, colsum2, score);

    final_kernel<<<1, 1, 0, stream>>>(colsum2, score, lb, out);
}